// Round 10
// baseline (267.116 us; speedup 1.0000x reference)
//
#include <hip/hip_runtime.h>

#define Bz 8
#define Lz 2048
#define Dz 256
#define Nz 64
#define SP 68   // b128-aligned LDS stride (powmm)
#define SA 65   // scalar-access LDS stride (conflict-free rows+cols)
#define SM 132  // out3 LDS stride
#define SG 136  // gemm2 dk-major stride (128 + 8)
#define KE 8    // Taylor order for E^r / E64 / W (norm(64*dt*A) ~ 0.08)
#define KP 11   // p-chain depth = KE + 3 (dB phi1 terms)

__device__ __forceinline__ float softplusf(float x) {
  return (x > 20.f) ? x : log1pf(expf(x));
}

// ---- power-basis kernels: Apow[k-1] = A^k (row-major 64x64), k=1..8 ----

__global__ __launch_bounds__(256) void s4_powinit(const float* __restrict__ log_A,
                                                  float* __restrict__ Apow) {
  const int i = blockIdx.x * 256 + threadIdx.x;
  Apow[i] = softplusf(log_A[i]);
}

// O(blockIdx) = Apow[li] * Apow[blockIdx]; writes Apow[oi + blockIdx].
__global__ __launch_bounds__(256, 1) void s4_powmm(const float* __restrict__ Apow_c,
                                                   float* __restrict__ Apow,
                                                   int li, int oi) {
  __shared__ alignas(16) float LA[Nz * SP];
  __shared__ alignas(16) float LB[Nz * SP];
  const int tid = threadIdx.x;
  const float* L = Apow_c + (size_t)li * 4096;
  const float* R = Apow_c + (size_t)blockIdx.x * 4096;
  float* O = Apow + (size_t)(oi + blockIdx.x) * 4096;
#pragma unroll
  for (int i = 0; i < 4; ++i) {
    const int e = (tid + 256 * i) * 4;
    const int r = e >> 6, c = e & 63;
    *(float4*)&LA[r * SP + c] = *(const float4*)(L + e);
    *(float4*)&LB[r * SP + c] = *(const float4*)(R + e);
  }
  __syncthreads();
  const int n = tid & 63, q = tid >> 6;
  float arow[64];
#pragma unroll
  for (int mm = 0; mm < 16; ++mm) {
    const float4 a4 = *(const float4*)(LA + n * SP + mm * 4);
    arow[4 * mm + 0] = a4.x; arow[4 * mm + 1] = a4.y;
    arow[4 * mm + 2] = a4.z; arow[4 * mm + 3] = a4.w;
  }
  float acc[16];
#pragma unroll
  for (int i = 0; i < 16; ++i) acc[i] = 0.f;
#pragma unroll 8
  for (int m = 0; m < 64; ++m) {
    const float4 b0 = *(const float4*)(LB + m * SP + q * 16 + 0);
    const float4 b1 = *(const float4*)(LB + m * SP + q * 16 + 4);
    const float4 b2 = *(const float4*)(LB + m * SP + q * 16 + 8);
    const float4 b3 = *(const float4*)(LB + m * SP + q * 16 + 12);
    const float a = arow[m];
    acc[0]  = fmaf(a, b0.x, acc[0]);  acc[1]  = fmaf(a, b0.y, acc[1]);
    acc[2]  = fmaf(a, b0.z, acc[2]);  acc[3]  = fmaf(a, b0.w, acc[3]);
    acc[4]  = fmaf(a, b1.x, acc[4]);  acc[5]  = fmaf(a, b1.y, acc[5]);
    acc[6]  = fmaf(a, b1.z, acc[6]);  acc[7]  = fmaf(a, b1.w, acc[7]);
    acc[8]  = fmaf(a, b2.x, acc[8]);  acc[9]  = fmaf(a, b2.y, acc[9]);
    acc[10] = fmaf(a, b2.z, acc[10]); acc[11] = fmaf(a, b2.w, acc[11]);
    acc[12] = fmaf(a, b3.x, acc[12]); acc[13] = fmaf(a, b3.y, acc[13]);
    acc[14] = fmaf(a, b3.z, acc[14]); acc[15] = fmaf(a, b3.w, acc[15]);
  }
#pragma unroll
  for (int v = 0; v < 4; ++v) {
    float4 o;
    o.x = acc[4 * v + 0]; o.y = acc[4 * v + 1];
    o.z = acc[4 * v + 2]; o.w = acc[4 * v + 3];
    *(float4*)(O + n * 64 + q * 16 + 4 * v) = o;
  }
}

// ---- per-d build: chained matvecs on shared A, emit small vectors ----
__global__ __launch_bounds__(256, 1) void s4_build2(
    const float* __restrict__ Apow, const float* __restrict__ Bp,
    const float* __restrict__ Cp, const float* __restrict__ log_delta,
    float* __restrict__ Gk, float* __restrict__ Qk,
    float* __restrict__ kloc, float* __restrict__ dts) {
  __shared__ float As[Nz * SA];
  __shared__ float Pst[KP + 1][Nz];
  __shared__ float Qst[KE + 1][Nz];
  __shared__ float Pv[Nz], Qv[Nz], dBs[Nz];
  __shared__ float prA[4][Nz + 8], prB[4][Nz + 8];
  __shared__ float zp[KE + 1][17], zs[KE + 1];
  const int tid = threadIdx.x;
  const int d = blockIdx.x;
  const int n = tid & 63, qq = tid >> 6;
  const float dt = softplusf(log_delta[d]) + 1e-6f;

#pragma unroll
  for (int i = 0; i < 4; ++i) {
    const int e = (tid + 256 * i) * 4;
    const int r = e >> 6, c = e & 63;
    const float4 v = *(const float4*)(Apow + e);
    As[r * SA + c] = v.x; As[r * SA + c + 1] = v.y;
    As[r * SA + c + 2] = v.z; As[r * SA + c + 3] = v.w;
  }
  if (tid < 64) {
    const float bv = Bp[d * Nz + tid], cv = Cp[d * Nz + tid];
    Pv[tid] = bv; Pst[0][tid] = bv;
    Qv[tid] = cv; Qst[0][tid] = cv;
  }
  __syncthreads();
#pragma unroll 1
  for (int k = 1; k <= KP; ++k) {
    float pp = 0.f, pq = 0.f;
#pragma unroll
    for (int mm = 0; mm < 16; ++mm) {
      const int m = qq * 16 + mm;
      pp += As[n * SA + m] * Pv[m];   // (A p)[n]
      pq += As[m * SA + n] * Qv[m];   // (A^T q)[n]
    }
    prA[qq][n] = pp; prB[qq][n] = pq;
    __syncthreads();
    if (tid < 64) {
      const float np = prA[0][tid] + prA[1][tid] + prA[2][tid] + prA[3][tid];
      Pv[tid] = np; Pst[k][tid] = np;
      if (k <= KE) {
        const float nq = prB[0][tid] + prB[1][tid] + prB[2][tid] + prB[3][tid];
        Qv[tid] = nq; Qst[k][tid] = nq;
      }
    }
    __syncthreads();
  }
  const float dtc0 = dt;
  const float dtc1 = dt * dt * 0.5f;
  const float dtc2 = dtc1 * dt * (1.f / 3.f);
  const float dtc3 = dtc2 * dt * 0.25f;
  if (tid < 64) {
    dBs[tid] = dtc0 * Pst[0][tid] + dtc1 * Pst[1][tid] +
               dtc2 * Pst[2][tid] + dtc3 * Pst[3][tid];
#pragma unroll
    for (int k = 0; k <= KE; ++k) {
      Gk[(size_t)d * ((KE + 1) * 64) + k * 64 + tid] =
          dtc0 * Pst[k][tid] + dtc1 * Pst[k + 1][tid] +
          dtc2 * Pst[k + 2][tid] + dtc3 * Pst[k + 3][tid];
      Qk[(size_t)d * ((KE + 1) * 64) + k * 64 + tid] = Qst[k][tid];
    }
  }
  __syncthreads();
  if (tid < (KE + 1) * 16) {
    const int k = tid >> 4, seg = tid & 15;
    float s = 0.f;
#pragma unroll
    for (int i = 0; i < 4; ++i) s += Qst[k][seg * 4 + i] * dBs[seg * 4 + i];
    zp[k][seg] = s;
  }
  __syncthreads();
  if (tid <= KE) {
    float s = 0.f;
#pragma unroll
    for (int seg = 0; seg < 16; ++seg) s += zp[tid][seg];
    zs[tid] = s;
  }
  __syncthreads();
  if (tid < 64) {
    const float rdt = (float)tid * dt;
    float c = 1.f, acc = zs[0];
#pragma unroll
    for (int k = 1; k <= KE; ++k) { c *= rdt / (float)k; acc += c * zs[k]; }
    kloc[d * 64 + tid] = acc;
  }
  if (tid == 0) dts[d] = dt;
}

// Transpose x[b][t][d] -> xT[d][b][t]. 64x64 LDS tiles.
__global__ __launch_bounds__(256) void s4_xt(const float* __restrict__ x,
                                             float* __restrict__ xT) {
  __shared__ float tile[64][65];
  const int t0 = blockIdx.x * 64, d0 = blockIdx.y * 64, b = blockIdx.z;
  const int lt = threadIdx.x & 63, rq = threadIdx.x >> 6;
#pragma unroll
  for (int i = 0; i < 16; ++i) {
    const int row = rq + i * 4;
    tile[row][lt] = x[((size_t)b * Lz + t0 + row) * Dz + d0 + lt];
  }
  __syncthreads();
#pragma unroll
  for (int i = 0; i < 16; ++i) {
    const int row = rq + i * 4;
    xT[((size_t)(d0 + row) * Bz + b) * Lz + t0 + lt] = tile[lt][row];
  }
}

// Chunked state scan v3, one block per d. E64 (incl identity) lives in LDS
// (r9: keeping both 64-row arrays in registers spilled at VGPR=92; only
// arowU stays in regs). Es reads are stride-65 scalar -> 2-way, free.
__global__ __launch_bounds__(256) void s4_scan3(
    const float* __restrict__ xT, const float* __restrict__ Apow,
    const float* __restrict__ Gk, const float* __restrict__ dts,
    float* __restrict__ S) {
  __shared__ float Es[Nz * SA];
  __shared__ float Gs[(KE + 1) * Nz];
  __shared__ float CT[KE + 1][66];
  __shared__ float Xs[8][64];
  __shared__ float Ss[8][64];
  const int d = blockIdx.x;
  const int tid = threadIdx.x, n = tid & 63, q = tid >> 6;
  const float dt = dts[d];
  if (tid < 65) {
    const float rdt = (float)tid * dt;
    float c = 1.f;
    CT[0][tid] = 1.f;
#pragma unroll
    for (int k = 1; k <= KE; ++k) { c *= rdt / (float)k; CT[k][tid] = c; }
  }
  for (int idx = tid; idx < (KE + 1) * 64; idx += 256)
    Gs[idx] = Gk[(size_t)d * ((KE + 1) * 64) + idx];
  // build E64 into LDS: each thread owns 16 elements, accumulated in regs
  {
    float ea[16];
#pragma unroll
    for (int i = 0; i < 16; ++i) ea[i] = 0.f;
    const float dt64 = 64.f * dt;
    float ce = 1.f;
#pragma unroll 1
    for (int k = 1; k <= KE; ++k) {
      ce *= dt64 / (float)k;
      const float* Ak = Apow + (size_t)(k - 1) * 4096;
#pragma unroll
      for (int i = 0; i < 16; ++i)
        ea[i] = fmaf(ce, Ak[tid + 256 * i], ea[i]);
    }
#pragma unroll
    for (int i = 0; i < 16; ++i) {
      const int e = tid + 256 * i;
      const int r = e >> 6, c = e & 63;
      Es[r * SA + c] = ea[i] + ((r == c) ? 1.f : 0.f);
    }
  }
  __syncthreads();
  float arowU[64];
#pragma unroll
  for (int j = 0; j < 64; ++j) {
    float u = 0.f;
#pragma unroll
    for (int k = 0; k <= KE; ++k) u = fmaf(CT[k][63 - j], Gs[k * 64 + n], u);
    arowU[j] = u;                 // = (E^{63-j} dB)[n]
  }
  Ss[q][n] = 0.f;
  Ss[q + 4][n] = 0.f;
  __syncthreads();
  const float* xd = xT + (size_t)d * Bz * Lz;
  float* Sd = S + (size_t)d * (32 * 8 * 64);
  const float* ern = Es + n * SA;
#pragma unroll 1
  for (int c = 0; c < 32; ++c) {
    Xs[q][n]     = xd[(size_t)q * Lz + c * 64 + n];
    Xs[q + 4][n] = xd[(size_t)(q + 4) * Lz + c * 64 + n];
    Sd[c * 512 + q * 64 + n]       = Ss[q][n];
    Sd[c * 512 + (q + 4) * 64 + n] = Ss[q + 4][n];
    __syncthreads();
    float acc0 = 0.f, acc1 = 0.f;
#pragma unroll
    for (int m = 0; m < 64; m += 4) {
      const float4 s0 = *(const float4*)&Ss[q][m];
      const float4 s1 = *(const float4*)&Ss[q + 4][m];
      const float4 x0 = *(const float4*)&Xs[q][m];
      const float4 x1 = *(const float4*)&Xs[q + 4][m];
      const float e0 = ern[m], e1 = ern[m + 1], e2 = ern[m + 2], e3 = ern[m + 3];
      acc0 = fmaf(e0, s0.x, acc0);           acc1 = fmaf(e0, s1.x, acc1);
      acc0 = fmaf(e1, s0.y, acc0);           acc1 = fmaf(e1, s1.y, acc1);
      acc0 = fmaf(e2, s0.z, acc0);           acc1 = fmaf(e2, s1.z, acc1);
      acc0 = fmaf(e3, s0.w, acc0);           acc1 = fmaf(e3, s1.w, acc1);
      acc0 = fmaf(arowU[m], x0.x, acc0);     acc1 = fmaf(arowU[m], x1.x, acc1);
      acc0 = fmaf(arowU[m + 1], x0.y, acc0); acc1 = fmaf(arowU[m + 1], x1.y, acc1);
      acc0 = fmaf(arowU[m + 2], x0.z, acc0); acc1 = fmaf(arowU[m + 2], x1.z, acc1);
      acc0 = fmaf(arowU[m + 3], x0.w, acc0); acc1 = fmaf(arowU[m + 3], x1.w, acc1);
    }
    __syncthreads();
    Ss[q][n] = acc0;
    Ss[q + 4][n] = acc1;
    __syncthreads();
  }
}

// Output as LDS-tiled GEMM: per d, y(64x256) = [W|T](64x128).[S;X](128x256)
__global__ __launch_bounds__(256, 1) void s4_out3(
    const float* __restrict__ xT, const float* __restrict__ S,
    const float* __restrict__ Qk, const float* __restrict__ kloc,
    const float* __restrict__ dts, float* __restrict__ yT) {
  __shared__ alignas(16) float Ms[64 * SM];   // [r][k]  k<64: W, k>=64: T
  __shared__ alignas(16) float Zs[64 * SM];   // [col][k] k<64: S, k>=64: X
  __shared__ float Qs[(KE + 1) * Nz];
  __shared__ float CT[KE + 1][66];
  __shared__ float kx[64];
  const int d = blockIdx.x;
  const int tid = threadIdx.x;
  const int tc = tid & 15, tr = tid >> 4;
  const float dt = dts[d];
  if (tid < 65) {
    const float rdt = (float)tid * dt;
    float c = 1.f;
    CT[0][tid] = 1.f;
#pragma unroll
    for (int k = 1; k <= KE; ++k) { c *= rdt / (float)k; CT[k][tid] = c; }
  }
  for (int idx = tid; idx < (KE + 1) * 64; idx += 256)
    Qs[idx] = Qk[(size_t)d * ((KE + 1) * 64) + idx];
  if (tid < 64) kx[tid] = kloc[d * 64 + tid];
  __syncthreads();
#pragma unroll
  for (int i = 0; i < 16; ++i) {
    const int e = tid + 256 * i;
    const int r = e >> 6, m = e & 63;
    float w = 0.f;
#pragma unroll
    for (int k = 0; k <= KE; ++k) w = fmaf(CT[k][r + 1], Qs[k * 64 + m], w);
    Ms[r * SM + m] = w;
  }
#pragma unroll
  for (int i = 0; i < 16; ++i) {
    const int e = tid + 256 * i;
    const int r = e >> 6, j = e & 63;
    Ms[r * SM + 64 + j] = (j <= r) ? kx[r - j] : 0.f;
  }
  const float* xd = xT + (size_t)d * Bz * Lz;
  const float* Sd = S + (size_t)d * (32 * 8 * 64);
  float* yd = yT + (size_t)d * Bz * Lz;
  const int lcol = tid >> 2, seg = tid & 3;
  const int sbb = lcol & 7, sccl = lcol >> 3;
#pragma unroll 1
  for (int ch = 0; ch < 4; ++ch) {
    {
      const int cc = ch * 8 + sccl;
      const float* sp = Sd + cc * 512 + sbb * 64 + seg * 16;
      const float* xp = xd + (size_t)sbb * Lz + cc * 64 + seg * 16;
      float* zrow = Zs + lcol * SM;
#pragma unroll
      for (int i = 0; i < 4; ++i) {
        *(float4*)(zrow + seg * 16 + i * 4) = *(const float4*)(sp + i * 4);
        *(float4*)(zrow + 64 + seg * 16 + i * 4) = *(const float4*)(xp + i * 4);
      }
    }
    __syncthreads();
    float acc[16];
#pragma unroll
    for (int i = 0; i < 16; ++i) acc[i] = 0.f;
#pragma unroll 4
    for (int k = 0; k < 128; k += 4) {
      float4 mv[4], zv[4];
#pragma unroll
      for (int i = 0; i < 4; ++i)
        mv[i] = *(const float4*)&Ms[(tr * 4 + i) * SM + k];
#pragma unroll
      for (int jj = 0; jj < 4; ++jj)
        zv[jj] = *(const float4*)&Zs[(tc + 16 * jj) * SM + k];
#pragma unroll
      for (int i = 0; i < 4; ++i)
#pragma unroll
        for (int jj = 0; jj < 4; ++jj) {
          acc[i * 4 + jj] = fmaf(mv[i].x, zv[jj].x, acc[i * 4 + jj]);
          acc[i * 4 + jj] = fmaf(mv[i].y, zv[jj].y, acc[i * 4 + jj]);
          acc[i * 4 + jj] = fmaf(mv[i].z, zv[jj].z, acc[i * 4 + jj]);
          acc[i * 4 + jj] = fmaf(mv[i].w, zv[jj].w, acc[i * 4 + jj]);
        }
    }
    __syncthreads();
#pragma unroll
    for (int i = 0; i < 4; ++i)
#pragma unroll
      for (int jj = 0; jj < 4; ++jj)
        Zs[(tc + 16 * jj) * SM + tr * 4 + i] = acc[i * 4 + jj];
    __syncthreads();
    {
      const int cc = ch * 8 + sccl;
      float* yp = yd + (size_t)sbb * Lz + cc * 64 + seg * 16;
      const float* zrow = Zs + lcol * SM;
#pragma unroll
      for (int i = 0; i < 4; ++i)
        *(float4*)(yp + i * 4) = *(const float4*)(zrow + seg * 16 + i * 4);
    }
    __syncthreads();
  }
}

// Final GEMM v2: 128x128 tile, 8x8 microtile (4 FMA per LDS float),
// dk-major LDS layout -> 16-consecutive-address reads, conflict-free.
// out[row,c] = sum_d (yT[d][row] + xT[d][row]*skip[d]) * W[c,d] + b[c]
__global__ __launch_bounds__(256) void s4_gemm2(
    const float* __restrict__ yT, const float* __restrict__ xT,
    const float* __restrict__ skip_D, const float* __restrict__ Wo,
    const float* __restrict__ bo, float* __restrict__ out) {
  __shared__ float Ys2[16 * SG];   // [dk][row]
  __shared__ float Ws2[16 * SG];   // [dk][col]
  const int tid = threadIdx.x;
  const int r0 = blockIdx.x * 128;      // 128 rows, single batch (128 | 2048)
  const int c0 = blockIdx.y * 128;
  const int brow = r0 >> 11;
  const int t0 = r0 & 2047;
  const int tr = tid >> 4, tc = tid & 15;
  const int ytt = tid & 127, ydh = tid >> 7;      // Ys staging roles
  const int wc = tid >> 1, wf = (tid & 1) * 8;    // Ws staging roles
  float acc[64];
#pragma unroll
  for (int i = 0; i < 64; ++i) acc[i] = 0.f;
#pragma unroll 1
  for (int kc = 0; kc < 16; ++kc) {
    const int dc0 = kc * 16;
    // stage Ys2: y + x*skip, coalesced over t (yT/xT are [d][b][t])
#pragma unroll
    for (int p = 0; p < 8; ++p) {
      const int dk = p * 2 + ydh;
      const int dd = dc0 + dk;
      const size_t off = ((size_t)dd * Bz + brow) * Lz + t0 + ytt;
      Ys2[dk * SG + ytt] = yT[off] + xT[off] * skip_D[dd];
    }
    // stage Ws2: transpose Wo rows into [dk][col]
    {
      const float4 w0 = *(const float4*)(Wo + (size_t)(c0 + wc) * Dz + dc0 + wf);
      const float4 w1 = *(const float4*)(Wo + (size_t)(c0 + wc) * Dz + dc0 + wf + 4);
      Ws2[(wf + 0) * SG + wc] = w0.x; Ws2[(wf + 1) * SG + wc] = w0.y;
      Ws2[(wf + 2) * SG + wc] = w0.z; Ws2[(wf + 3) * SG + wc] = w0.w;
      Ws2[(wf + 4) * SG + wc] = w1.x; Ws2[(wf + 5) * SG + wc] = w1.y;
      Ws2[(wf + 6) * SG + wc] = w1.z; Ws2[(wf + 7) * SG + wc] = w1.w;
    }
    __syncthreads();
#pragma unroll
    for (int dk = 0; dk < 16; ++dk) {
      float av[8], bv[8];
#pragma unroll
      for (int i = 0; i < 8; ++i) av[i] = Ys2[dk * SG + tr + 16 * i];
#pragma unroll
      for (int jj = 0; jj < 8; ++jj) bv[jj] = Ws2[dk * SG + tc + 16 * jj];
#pragma unroll
      for (int i = 0; i < 8; ++i)
#pragma unroll
        for (int jj = 0; jj < 8; ++jj)
          acc[i * 8 + jj] = fmaf(av[i], bv[jj], acc[i * 8 + jj]);
    }
    __syncthreads();
  }
  float bb[8];
#pragma unroll
  for (int jj = 0; jj < 8; ++jj) bb[jj] = bo[c0 + tc + 16 * jj];
#pragma unroll
  for (int i = 0; i < 8; ++i) {
    float* op = out + (size_t)(r0 + tr + 16 * i) * Dz + c0 + tc;
#pragma unroll
    for (int jj = 0; jj < 8; ++jj)
      op[16 * jj] = acc[i * 8 + jj] + bb[jj];
  }
}

extern "C" void kernel_launch(void* const* d_in, const int* in_sizes, int n_in,
                              void* d_out, int out_size, void* d_ws, size_t ws_size,
                              hipStream_t stream) {
  const float* x         = (const float*)d_in[0];
  const float* log_A     = (const float*)d_in[1];
  const float* Bp        = (const float*)d_in[2];
  const float* Cp        = (const float*)d_in[3];
  const float* log_delta = (const float*)d_in[4];
  const float* skip_D    = (const float*)d_in[5];
  const float* W_out     = (const float*)d_in[6];
  const float* b_out     = (const float*)d_in[7];
  float* out = (float*)d_out;

  float* xT   = (float*)d_ws;
  float* yT   = xT + (size_t)Dz * Bz * Lz;
  float* S    = yT + (size_t)Dz * Bz * Lz;
  float* Apow = S + (size_t)Dz * (32 * 8 * 64);
  float* Gk   = Apow + (size_t)8 * 4096;
  float* Qk   = Gk + (size_t)Dz * (KE + 1) * 64;
  float* kloc = Qk + (size_t)Dz * (KE + 1) * 64;
  float* dts  = kloc + (size_t)Dz * 64;

  hipLaunchKernelGGL(s4_xt, dim3(Lz / 64, Dz / 64, Bz), dim3(256), 0, stream,
                     x, xT);
  hipLaunchKernelGGL(s4_powinit, dim3(16), dim3(256), 0, stream, log_A, Apow);
  hipLaunchKernelGGL(s4_powmm, dim3(1), dim3(256), 0, stream, Apow, Apow, 0, 1);
  hipLaunchKernelGGL(s4_powmm, dim3(2), dim3(256), 0, stream, Apow, Apow, 1, 2);
  hipLaunchKernelGGL(s4_powmm, dim3(4), dim3(256), 0, stream, Apow, Apow, 3, 4);
  hipLaunchKernelGGL(s4_build2, dim3(Dz), dim3(256), 0, stream,
                     Apow, Bp, Cp, log_delta, Gk, Qk, kloc, dts);
  hipLaunchKernelGGL(s4_scan3, dim3(Dz), dim3(256), 0, stream,
                     xT, Apow, Gk, dts, S);
  hipLaunchKernelGGL(s4_out3, dim3(Dz), dim3(256), 0, stream,
                     xT, S, Qk, kloc, dts, yT);
  hipLaunchKernelGGL(s4_gemm2, dim3((Bz * Lz) / 128, Dz / 128), dim3(256), 0, stream,
                     yT, xT, skip_D, W_out, b_out, out);
}

// Round 11
// 209.407 us; speedup vs baseline: 1.2756x; 1.2756x over previous
//
#include <hip/hip_runtime.h>

#define Bz 8
#define Lz 2048
#define Dz 256
#define Nz 64
#define SP 68   // b128-aligned LDS stride (powmm)
#define SA 65   // scalar-access LDS stride (conflict-free rows+cols)
#define SM 132  // out3 LDS stride
#define SG 136  // gemm3 Ys stride (16B-aligned rows)
#define SW 73   // gemm3 Ws stride (odd -> conflict-free transposed writes)
#define KE 4    // Taylor order: ||64*dt*A|| <= ~0.15 -> rel err ~6e-7
#define KP 7    // p-chain depth = KE + 3 (dB phi1 terms)
#define BSP 2   // scan: blocks per channel (batch split)
#define BPB (Bz / BSP)

__device__ __forceinline__ float softplusf(float x) {
  return (x > 20.f) ? x : log1pf(expf(x));
}

// ---- Transpose x[b][t][d] -> xT[d][b][t]; also folds powinit (A = softplus). ----
__global__ __launch_bounds__(256) void s4_xt(const float* __restrict__ x,
                                             float* __restrict__ xT,
                                             const float* __restrict__ log_A,
                                             float* __restrict__ Apow) {
  if (blockIdx.x == 0 && blockIdx.y == 0) {
    const int i = blockIdx.z * 512 + threadIdx.x;
    Apow[i] = softplusf(log_A[i]);
    Apow[i + 256] = softplusf(log_A[i + 256]);
  }
  __shared__ float tile[64][65];
  const int t0 = blockIdx.x * 64, d0 = blockIdx.y * 64, b = blockIdx.z;
  const int lt = threadIdx.x & 63, rq = threadIdx.x >> 6;
#pragma unroll
  for (int i = 0; i < 16; ++i) {
    const int row = rq + i * 4;
    tile[row][lt] = x[((size_t)b * Lz + t0 + row) * Dz + d0 + lt];
  }
  __syncthreads();
#pragma unroll
  for (int i = 0; i < 16; ++i) {
    const int row = rq + i * 4;
    xT[((size_t)(d0 + row) * Bz + b) * Lz + t0 + lt] = tile[lt][row];
  }
}

// O(blockIdx) = Apow[li] * Apow[blockIdx]; writes Apow[oi + blockIdx].
// launch1: li=0,oi=1,grid=1 (A2); launch2: li=1,oi=2,grid=2 (A3,A4).
__global__ __launch_bounds__(256, 1) void s4_powmm(const float* __restrict__ Apow_c,
                                                   float* __restrict__ Apow,
                                                   int li, int oi) {
  __shared__ alignas(16) float LA[Nz * SP];
  __shared__ alignas(16) float LB[Nz * SP];
  const int tid = threadIdx.x;
  const float* L = Apow_c + (size_t)li * 4096;
  const float* R = Apow_c + (size_t)blockIdx.x * 4096;
  float* O = Apow + (size_t)(oi + blockIdx.x) * 4096;
#pragma unroll
  for (int i = 0; i < 4; ++i) {
    const int e = (tid + 256 * i) * 4;
    const int r = e >> 6, c = e & 63;
    *(float4*)&LA[r * SP + c] = *(const float4*)(L + e);
    *(float4*)&LB[r * SP + c] = *(const float4*)(R + e);
  }
  __syncthreads();
  const int n = tid & 63, q = tid >> 6;
  float arow[64];
#pragma unroll
  for (int mm = 0; mm < 16; ++mm) {
    const float4 a4 = *(const float4*)(LA + n * SP + mm * 4);
    arow[4 * mm + 0] = a4.x; arow[4 * mm + 1] = a4.y;
    arow[4 * mm + 2] = a4.z; arow[4 * mm + 3] = a4.w;
  }
  float acc[16];
#pragma unroll
  for (int i = 0; i < 16; ++i) acc[i] = 0.f;
#pragma unroll 8
  for (int m = 0; m < 64; ++m) {
    const float4 b0 = *(const float4*)(LB + m * SP + q * 16 + 0);
    const float4 b1 = *(const float4*)(LB + m * SP + q * 16 + 4);
    const float4 b2 = *(const float4*)(LB + m * SP + q * 16 + 8);
    const float4 b3 = *(const float4*)(LB + m * SP + q * 16 + 12);
    const float a = arow[m];
    acc[0]  = fmaf(a, b0.x, acc[0]);  acc[1]  = fmaf(a, b0.y, acc[1]);
    acc[2]  = fmaf(a, b0.z, acc[2]);  acc[3]  = fmaf(a, b0.w, acc[3]);
    acc[4]  = fmaf(a, b1.x, acc[4]);  acc[5]  = fmaf(a, b1.y, acc[5]);
    acc[6]  = fmaf(a, b1.z, acc[6]);  acc[7]  = fmaf(a, b1.w, acc[7]);
    acc[8]  = fmaf(a, b2.x, acc[8]);  acc[9]  = fmaf(a, b2.y, acc[9]);
    acc[10] = fmaf(a, b2.z, acc[10]); acc[11] = fmaf(a, b2.w, acc[11]);
    acc[12] = fmaf(a, b3.x, acc[12]); acc[13] = fmaf(a, b3.y, acc[13]);
    acc[14] = fmaf(a, b3.z, acc[14]); acc[15] = fmaf(a, b3.w, acc[15]);
  }
#pragma unroll
  for (int v = 0; v < 4; ++v) {
    float4 o;
    o.x = acc[4 * v + 0]; o.y = acc[4 * v + 1];
    o.z = acc[4 * v + 2]; o.w = acc[4 * v + 3];
    *(float4*)(O + n * 64 + q * 16 + 4 * v) = o;
  }
}

// ---- per-d build: chained matvecs on shared A, emit small vectors ----
__global__ __launch_bounds__(256, 1) void s4_build2(
    const float* __restrict__ Apow, const float* __restrict__ Bp,
    const float* __restrict__ Cp, const float* __restrict__ log_delta,
    float* __restrict__ Gk, float* __restrict__ Qk,
    float* __restrict__ kloc, float* __restrict__ dts) {
  __shared__ float As[Nz * SA];
  __shared__ float Pst[KP + 1][Nz];
  __shared__ float Qst[KE + 1][Nz];
  __shared__ float Pv[Nz], Qv[Nz], dBs[Nz];
  __shared__ float prA[4][Nz + 8], prB[4][Nz + 8];
  __shared__ float zp[KE + 1][17], zs[KE + 1];
  const int tid = threadIdx.x;
  const int d = blockIdx.x;
  const int n = tid & 63, qq = tid >> 6;
  const float dt = softplusf(log_delta[d]) + 1e-6f;

#pragma unroll
  for (int i = 0; i < 4; ++i) {
    const int e = (tid + 256 * i) * 4;
    const int r = e >> 6, c = e & 63;
    const float4 v = *(const float4*)(Apow + e);
    As[r * SA + c] = v.x; As[r * SA + c + 1] = v.y;
    As[r * SA + c + 2] = v.z; As[r * SA + c + 3] = v.w;
  }
  if (tid < 64) {
    const float bv = Bp[d * Nz + tid], cv = Cp[d * Nz + tid];
    Pv[tid] = bv; Pst[0][tid] = bv;
    Qv[tid] = cv; Qst[0][tid] = cv;
  }
  __syncthreads();
#pragma unroll 1
  for (int k = 1; k <= KP; ++k) {
    float pp = 0.f, pq = 0.f;
#pragma unroll
    for (int mm = 0; mm < 16; ++mm) {
      const int m = qq * 16 + mm;
      pp += As[n * SA + m] * Pv[m];   // (A p)[n]
      pq += As[m * SA + n] * Qv[m];   // (A^T q)[n]
    }
    prA[qq][n] = pp; prB[qq][n] = pq;
    __syncthreads();
    if (tid < 64) {
      const float np = prA[0][tid] + prA[1][tid] + prA[2][tid] + prA[3][tid];
      Pv[tid] = np; Pst[k][tid] = np;
      if (k <= KE) {
        const float nq = prB[0][tid] + prB[1][tid] + prB[2][tid] + prB[3][tid];
        Qv[tid] = nq; Qst[k][tid] = nq;
      }
    }
    __syncthreads();
  }
  const float dtc0 = dt;
  const float dtc1 = dt * dt * 0.5f;
  const float dtc2 = dtc1 * dt * (1.f / 3.f);
  const float dtc3 = dtc2 * dt * 0.25f;
  if (tid < 64) {
    dBs[tid] = dtc0 * Pst[0][tid] + dtc1 * Pst[1][tid] +
               dtc2 * Pst[2][tid] + dtc3 * Pst[3][tid];
#pragma unroll
    for (int k = 0; k <= KE; ++k) {
      Gk[(size_t)d * ((KE + 1) * 64) + k * 64 + tid] =
          dtc0 * Pst[k][tid] + dtc1 * Pst[k + 1][tid] +
          dtc2 * Pst[k + 2][tid] + dtc3 * Pst[k + 3][tid];
      Qk[(size_t)d * ((KE + 1) * 64) + k * 64 + tid] = Qst[k][tid];
    }
  }
  __syncthreads();
  if (tid < (KE + 1) * 16) {
    const int k = tid >> 4, seg = tid & 15;
    float s = 0.f;
#pragma unroll
    for (int i = 0; i < 4; ++i) s += Qst[k][seg * 4 + i] * dBs[seg * 4 + i];
    zp[k][seg] = s;
  }
  __syncthreads();
  if (tid <= KE) {
    float s = 0.f;
#pragma unroll
    for (int seg = 0; seg < 16; ++seg) s += zp[tid][seg];
    zs[tid] = s;
  }
  __syncthreads();
  if (tid < 64) {
    const float rdt = (float)tid * dt;
    float c = 1.f, acc = zs[0];
#pragma unroll
    for (int k = 1; k <= KE; ++k) { c *= rdt / (float)k; acc += c * zs[k]; }
    kloc[d * 64 + tid] = acc;
  }
  if (tid == 0) dts[d] = dt;
}

// Chunked state scan v4. Grid (Dz, BSP): block handles BPB=4 batches of
// one d -> 512 blocks = 2/CU (barriers overlap across blocks). Dot products
// split across the 4 wave-groups: thread (n,q) holds Er[16], Ur[16]
// (16-element constant-indexed arrays -> never spilled), partials reduced
// via LDS. All inner LDS reads are wave-broadcast b128.
__global__ __launch_bounds__(256, 2) void s4_scan4(
    const float* __restrict__ xT, const float* __restrict__ Apow,
    const float* __restrict__ Gk, const float* __restrict__ dts,
    float* __restrict__ S) {
  __shared__ float Es[Nz * SA];
  __shared__ float Gs[(KE + 1) * Nz];
  __shared__ float CTs[KE + 1][66];
  __shared__ alignas(16) float Xs[BPB][64];
  __shared__ alignas(16) float Ss[BPB][64];
  __shared__ float pr[4][BPB][64];
  const int d = blockIdx.x;
  const int z = blockIdx.y;
  const int tid = threadIdx.x, n = tid & 63, q = tid >> 6;
  const int rb = tid >> 6;               // reduce ownership: (rb, n)
  const float dt = dts[d];
  if (tid < 65) {
    const float rdt = (float)tid * dt;
    float c = 1.f;
    CTs[0][tid] = 1.f;
#pragma unroll
    for (int k = 1; k <= KE; ++k) { c *= rdt / (float)k; CTs[k][tid] = c; }
  }
  for (int idx = tid; idx < (KE + 1) * 64; idx += 256)
    Gs[idx] = Gk[(size_t)d * ((KE + 1) * 64) + idx];
  // E64 (incl identity) into LDS; each thread owns 16 elements.
  {
    float ea[16];
#pragma unroll
    for (int i = 0; i < 16; ++i) ea[i] = 0.f;
    const float dt64 = 64.f * dt;
    float ce = 1.f;
#pragma unroll 1
    for (int k = 1; k <= KE; ++k) {
      ce *= dt64 / (float)k;
      const float* Ak = Apow + (size_t)(k - 1) * 4096;
#pragma unroll
      for (int i = 0; i < 16; ++i)
        ea[i] = fmaf(ce, Ak[tid + 256 * i], ea[i]);
    }
#pragma unroll
    for (int i = 0; i < 16; ++i) {
      const int e = tid + 256 * i;
      const int r = e >> 6, c = e & 63;
      Es[r * SA + c] = ea[i] + ((r == c) ? 1.f : 0.f);
    }
  }
  __syncthreads();
  float Er[16], Ur[16];
#pragma unroll
  for (int i = 0; i < 16; ++i) Er[i] = Es[n * SA + q * 16 + i];
#pragma unroll
  for (int i = 0; i < 16; ++i) {
    const int j = q * 16 + i;
    float u = 0.f;
#pragma unroll
    for (int k = 0; k <= KE; ++k) u = fmaf(CTs[k][63 - j], Gs[k * 64 + n], u);
    Ur[i] = u;                    // = Uf[n][j] = (E^{63-j} dB)[n]
  }
  Ss[rb][n] = 0.f;
  const float* xd = xT + ((size_t)d * Bz + z * BPB) * Lz;
  float* Sd = S + (size_t)d * (32 * 8 * 64) + (size_t)(z * BPB) * 64;
#pragma unroll 1
  for (int c = 0; c < 32; ++c) {
    Xs[rb][n] = xd[(size_t)rb * Lz + c * 64 + n];
    Sd[c * 512 + rb * 64 + n] = Ss[rb][n];     // state entering chunk c
    __syncthreads();                            // B1: Xs/Ss ready
    float acc[BPB];
#pragma unroll
    for (int b = 0; b < BPB; ++b) {
      const float4 s0 = *(const float4*)&Ss[b][q * 16 + 0];
      const float4 s1 = *(const float4*)&Ss[b][q * 16 + 4];
      const float4 s2 = *(const float4*)&Ss[b][q * 16 + 8];
      const float4 s3 = *(const float4*)&Ss[b][q * 16 + 12];
      const float4 x0 = *(const float4*)&Xs[b][q * 16 + 0];
      const float4 x1 = *(const float4*)&Xs[b][q * 16 + 4];
      const float4 x2 = *(const float4*)&Xs[b][q * 16 + 8];
      const float4 x3 = *(const float4*)&Xs[b][q * 16 + 12];
      float a = 0.f;
      a = fmaf(Er[0], s0.x, a);  a = fmaf(Er[1], s0.y, a);
      a = fmaf(Er[2], s0.z, a);  a = fmaf(Er[3], s0.w, a);
      a = fmaf(Er[4], s1.x, a);  a = fmaf(Er[5], s1.y, a);
      a = fmaf(Er[6], s1.z, a);  a = fmaf(Er[7], s1.w, a);
      a = fmaf(Er[8], s2.x, a);  a = fmaf(Er[9], s2.y, a);
      a = fmaf(Er[10], s2.z, a); a = fmaf(Er[11], s2.w, a);
      a = fmaf(Er[12], s3.x, a); a = fmaf(Er[13], s3.y, a);
      a = fmaf(Er[14], s3.z, a); a = fmaf(Er[15], s3.w, a);
      a = fmaf(Ur[0], x0.x, a);  a = fmaf(Ur[1], x0.y, a);
      a = fmaf(Ur[2], x0.z, a);  a = fmaf(Ur[3], x0.w, a);
      a = fmaf(Ur[4], x1.x, a);  a = fmaf(Ur[5], x1.y, a);
      a = fmaf(Ur[6], x1.z, a);  a = fmaf(Ur[7], x1.w, a);
      a = fmaf(Ur[8], x2.x, a);  a = fmaf(Ur[9], x2.y, a);
      a = fmaf(Ur[10], x2.z, a); a = fmaf(Ur[11], x2.w, a);
      a = fmaf(Ur[12], x3.x, a); a = fmaf(Ur[13], x3.y, a);
      a = fmaf(Ur[14], x3.z, a); a = fmaf(Ur[15], x3.w, a);
      acc[b] = a;
    }
#pragma unroll
    for (int b = 0; b < BPB; ++b) pr[q][b][n] = acc[b];
    __syncthreads();                            // B2: pr ready, Ss/Xs reads done
    Ss[rb][n] = pr[0][rb][n] + pr[1][rb][n] + pr[2][rb][n] + pr[3][rb][n];
    __syncthreads();                            // B3: Ss updated, pr reads done
  }
}

// Output as LDS-tiled GEMM: per d, y(64x256) = [W|T](64x128).[S;X](128x256)
__global__ __launch_bounds__(256, 1) void s4_out3(
    const float* __restrict__ xT, const float* __restrict__ S,
    const float* __restrict__ Qk, const float* __restrict__ kloc,
    const float* __restrict__ dts, float* __restrict__ yT) {
  __shared__ alignas(16) float Ms[64 * SM];   // [r][k]  k<64: W, k>=64: T
  __shared__ alignas(16) float Zs[64 * SM];   // [col][k] k<64: S, k>=64: X
  __shared__ float Qs[(KE + 1) * Nz];
  __shared__ float CT[KE + 1][66];
  __shared__ float kx[64];
  const int d = blockIdx.x;
  const int tid = threadIdx.x;
  const int tc = tid & 15, tr = tid >> 4;
  const float dt = dts[d];
  if (tid < 65) {
    const float rdt = (float)tid * dt;
    float c = 1.f;
    CT[0][tid] = 1.f;
#pragma unroll
    for (int k = 1; k <= KE; ++k) { c *= rdt / (float)k; CT[k][tid] = c; }
  }
  for (int idx = tid; idx < (KE + 1) * 64; idx += 256)
    Qs[idx] = Qk[(size_t)d * ((KE + 1) * 64) + idx];
  if (tid < 64) kx[tid] = kloc[d * 64 + tid];
  __syncthreads();
#pragma unroll
  for (int i = 0; i < 16; ++i) {
    const int e = tid + 256 * i;
    const int r = e >> 6, m = e & 63;
    float w = 0.f;
#pragma unroll
    for (int k = 0; k <= KE; ++k) w = fmaf(CT[k][r + 1], Qs[k * 64 + m], w);
    Ms[r * SM + m] = w;
  }
#pragma unroll
  for (int i = 0; i < 16; ++i) {
    const int e = tid + 256 * i;
    const int r = e >> 6, j = e & 63;
    Ms[r * SM + 64 + j] = (j <= r) ? kx[r - j] : 0.f;
  }
  const float* xd = xT + (size_t)d * Bz * Lz;
  const float* Sd = S + (size_t)d * (32 * 8 * 64);
  float* yd = yT + (size_t)d * Bz * Lz;
  const int lcol = tid >> 2, seg = tid & 3;
  const int sbb = lcol & 7, sccl = lcol >> 3;
#pragma unroll 1
  for (int ch = 0; ch < 4; ++ch) {
    {
      const int cc = ch * 8 + sccl;
      const float* sp = Sd + cc * 512 + sbb * 64 + seg * 16;
      const float* xp = xd + (size_t)sbb * Lz + cc * 64 + seg * 16;
      float* zrow = Zs + lcol * SM;
#pragma unroll
      for (int i = 0; i < 4; ++i) {
        *(float4*)(zrow + seg * 16 + i * 4) = *(const float4*)(sp + i * 4);
        *(float4*)(zrow + 64 + seg * 16 + i * 4) = *(const float4*)(xp + i * 4);
      }
    }
    __syncthreads();
    float acc[16];
#pragma unroll
    for (int i = 0; i < 16; ++i) acc[i] = 0.f;
#pragma unroll 4
    for (int k = 0; k < 128; k += 4) {
      float4 mv[4], zv[4];
#pragma unroll
      for (int i = 0; i < 4; ++i)
        mv[i] = *(const float4*)&Ms[(tr * 4 + i) * SM + k];
#pragma unroll
      for (int jj = 0; jj < 4; ++jj)
        zv[jj] = *(const float4*)&Zs[(tc + 16 * jj) * SM + k];
#pragma unroll
      for (int i = 0; i < 4; ++i)
#pragma unroll
        for (int jj = 0; jj < 4; ++jj) {
          acc[i * 4 + jj] = fmaf(mv[i].x, zv[jj].x, acc[i * 4 + jj]);
          acc[i * 4 + jj] = fmaf(mv[i].y, zv[jj].y, acc[i * 4 + jj]);
          acc[i * 4 + jj] = fmaf(mv[i].z, zv[jj].z, acc[i * 4 + jj]);
          acc[i * 4 + jj] = fmaf(mv[i].w, zv[jj].w, acc[i * 4 + jj]);
        }
    }
    __syncthreads();
#pragma unroll
    for (int i = 0; i < 4; ++i)
#pragma unroll
      for (int jj = 0; jj < 4; ++jj)
        Zs[(tc + 16 * jj) * SM + tr * 4 + i] = acc[i * 4 + jj];
    __syncthreads();
    {
      const int cc = ch * 8 + sccl;
      float* yp = yd + (size_t)sbb * Lz + cc * 64 + seg * 16;
      const float* zrow = Zs + lcol * SM;
#pragma unroll
      for (int i = 0; i < 4; ++i)
        *(float4*)(yp + i * 4) = *(const float4*)(zrow + seg * 16 + i * 4);
    }
    __syncthreads();
  }
}

// Final GEMM v3: 128x64 tile, 8x4 microtile, grid 512 = 2 blocks/CU.
// A-operand reads are b128 (contiguous rows per thread).
__global__ __launch_bounds__(256, 2) void s4_gemm3(
    const float* __restrict__ yT, const float* __restrict__ xT,
    const float* __restrict__ skip_D, const float* __restrict__ Wo,
    const float* __restrict__ bo, float* __restrict__ out) {
  __shared__ alignas(16) float Ys2[16 * SG];   // [dk][row 0..127]
  __shared__ float Ws2[16 * SW];               // [dk][col 0..63]
  const int tid = threadIdx.x;
  const int r0 = blockIdx.x * 128;
  const int c0 = blockIdx.y * 64;
  const int brow = r0 >> 11;
  const int t0 = r0 & 2047;
  const int tr = tid >> 4, tc = tid & 15;
  const int ytt = tid & 127, ydh = tid >> 7;
  const int wr = tid >> 2, wq = tid & 3;
  float acc[32];
#pragma unroll
  for (int i = 0; i < 32; ++i) acc[i] = 0.f;
#pragma unroll 1
  for (int kc = 0; kc < 16; ++kc) {
    const int dc0 = kc * 16;
#pragma unroll
    for (int p = 0; p < 8; ++p) {
      const int dk = p * 2 + ydh;
      const int dd = dc0 + dk;
      const size_t off = ((size_t)dd * Bz + brow) * Lz + t0 + ytt;
      Ys2[dk * SG + ytt] = yT[off] + xT[off] * skip_D[dd];
    }
    {
      const float4 w4 = *(const float4*)(Wo + (size_t)(c0 + wr) * Dz + dc0 + wq * 4);
      Ws2[(wq * 4 + 0) * SW + wr] = w4.x;
      Ws2[(wq * 4 + 1) * SW + wr] = w4.y;
      Ws2[(wq * 4 + 2) * SW + wr] = w4.z;
      Ws2[(wq * 4 + 3) * SW + wr] = w4.w;
    }
    __syncthreads();
#pragma unroll
    for (int dk = 0; dk < 16; ++dk) {
      const float4 a0 = *(const float4*)&Ys2[dk * SG + tr * 8];
      const float4 a1 = *(const float4*)&Ys2[dk * SG + tr * 8 + 4];
      float bv[4];
#pragma unroll
      for (int jj = 0; jj < 4; ++jj) bv[jj] = Ws2[dk * SW + tc + 16 * jj];
#pragma unroll
      for (int jj = 0; jj < 4; ++jj) {
        acc[0 * 4 + jj] = fmaf(a0.x, bv[jj], acc[0 * 4 + jj]);
        acc[1 * 4 + jj] = fmaf(a0.y, bv[jj], acc[1 * 4 + jj]);
        acc[2 * 4 + jj] = fmaf(a0.z, bv[jj], acc[2 * 4 + jj]);
        acc[3 * 4 + jj] = fmaf(a0.w, bv[jj], acc[3 * 4 + jj]);
        acc[4 * 4 + jj] = fmaf(a1.x, bv[jj], acc[4 * 4 + jj]);
        acc[5 * 4 + jj] = fmaf(a1.y, bv[jj], acc[5 * 4 + jj]);
        acc[6 * 4 + jj] = fmaf(a1.z, bv[jj], acc[6 * 4 + jj]);
        acc[7 * 4 + jj] = fmaf(a1.w, bv[jj], acc[7 * 4 + jj]);
      }
    }
    __syncthreads();
  }
  float bb[4];
#pragma unroll
  for (int jj = 0; jj < 4; ++jj) bb[jj] = bo[c0 + tc + 16 * jj];
#pragma unroll
  for (int i = 0; i < 8; ++i) {
    float* op = out + (size_t)(r0 + tr * 8 + i) * Dz + c0 + tc;
#pragma unroll
    for (int jj = 0; jj < 4; ++jj)
      op[16 * jj] = acc[i * 4 + jj] + bb[jj];
  }
}

extern "C" void kernel_launch(void* const* d_in, const int* in_sizes, int n_in,
                              void* d_out, int out_size, void* d_ws, size_t ws_size,
                              hipStream_t stream) {
  const float* x         = (const float*)d_in[0];
  const float* log_A     = (const float*)d_in[1];
  const float* Bp        = (const float*)d_in[2];
  const float* Cp        = (const float*)d_in[3];
  const float* log_delta = (const float*)d_in[4];
  const float* skip_D    = (const float*)d_in[5];
  const float* W_out     = (const float*)d_in[6];
  const float* b_out     = (const float*)d_in[7];
  float* out = (float*)d_out;

  float* xT   = (float*)d_ws;
  float* yT   = xT + (size_t)Dz * Bz * Lz;
  float* S    = yT + (size_t)Dz * Bz * Lz;
  float* Apow = S + (size_t)Dz * (32 * 8 * 64);
  float* Gk   = Apow + (size_t)8 * 4096;
  float* Qk   = Gk + (size_t)Dz * (KE + 1) * 64;
  float* kloc = Qk + (size_t)Dz * (KE + 1) * 64;
  float* dts  = kloc + (size_t)Dz * 64;

  hipLaunchKernelGGL(s4_xt, dim3(Lz / 64, Dz / 64, Bz), dim3(256), 0, stream,
                     x, xT, log_A, Apow);
  hipLaunchKernelGGL(s4_powmm, dim3(1), dim3(256), 0, stream, Apow, Apow, 0, 1);
  hipLaunchKernelGGL(s4_powmm, dim3(2), dim3(256), 0, stream, Apow, Apow, 1, 2);
  hipLaunchKernelGGL(s4_build2, dim3(Dz), dim3(256), 0, stream,
                     Apow, Bp, Cp, log_delta, Gk, Qk, kloc, dts);
  hipLaunchKernelGGL(s4_scan4, dim3(Dz, BSP), dim3(256), 0, stream,
                     xT, Apow, Gk, dts, S);
  hipLaunchKernelGGL(s4_out3, dim3(Dz), dim3(256), 0, stream,
                     xT, S, Qk, kloc, dts, yT);
  hipLaunchKernelGGL(s4_gemm3, dim3((Bz * Lz) / 128, Dz / 64), dim3(256), 0, stream,
                     yT, xT, skip_D, W_out, b_out, out);
}

// Round 12
// 197.798 us; speedup vs baseline: 1.3505x; 1.0587x over previous
//
#include <hip/hip_runtime.h>

#define Bz 8
#define Lz 2048
#define Dz 256
#define Nz 64
#define SP 68   // b128-aligned LDS stride (powmm)
#define SA 65   // scalar-access LDS stride (conflict-free rows+cols)
#define SM 132  // out4 LDS stride
#define SG 136  // gemm3 Ys stride (16B-aligned rows)
#define SW 73   // gemm3 Ws stride (odd -> conflict-free transposed writes)
#define KE 4    // Taylor order: ||64*dt*A|| <= ~0.15 -> rel err ~6e-7
#define KP 7    // p-chain depth = KE + 3 (dB phi1 terms)
#define BSP 4   // scan: blocks per channel (batch split)
#define BPB (Bz / BSP)   // 2 batches per block

__device__ __forceinline__ float softplusf(float x) {
  return (x > 20.f) ? x : log1pf(expf(x));
}

// ---- Transpose x[b][t][d] -> xT[d][b][t]; also folds powinit (A = softplus). ----
__global__ __launch_bounds__(256) void s4_xt(const float* __restrict__ x,
                                             float* __restrict__ xT,
                                             const float* __restrict__ log_A,
                                             float* __restrict__ Apow) {
  if (blockIdx.x == 0 && blockIdx.y == 0) {
    const int i = blockIdx.z * 512 + threadIdx.x;
    Apow[i] = softplusf(log_A[i]);
    Apow[i + 256] = softplusf(log_A[i + 256]);
  }
  __shared__ float tile[64][65];
  const int t0 = blockIdx.x * 64, d0 = blockIdx.y * 64, b = blockIdx.z;
  const int lt = threadIdx.x & 63, rq = threadIdx.x >> 6;
#pragma unroll
  for (int i = 0; i < 16; ++i) {
    const int row = rq + i * 4;
    tile[row][lt] = x[((size_t)b * Lz + t0 + row) * Dz + d0 + lt];
  }
  __syncthreads();
#pragma unroll
  for (int i = 0; i < 16; ++i) {
    const int row = rq + i * 4;
    xT[((size_t)(d0 + row) * Bz + b) * Lz + t0 + lt] = tile[lt][row];
  }
}

// O(blockIdx) = Apow[li] * Apow[blockIdx]; writes Apow[oi + blockIdx].
__global__ __launch_bounds__(256, 1) void s4_powmm(const float* __restrict__ Apow_c,
                                                   float* __restrict__ Apow,
                                                   int li, int oi) {
  __shared__ alignas(16) float LA[Nz * SP];
  __shared__ alignas(16) float LB[Nz * SP];
  const int tid = threadIdx.x;
  const float* L = Apow_c + (size_t)li * 4096;
  const float* R = Apow_c + (size_t)blockIdx.x * 4096;
  float* O = Apow + (size_t)(oi + blockIdx.x) * 4096;
#pragma unroll
  for (int i = 0; i < 4; ++i) {
    const int e = (tid + 256 * i) * 4;
    const int r = e >> 6, c = e & 63;
    *(float4*)&LA[r * SP + c] = *(const float4*)(L + e);
    *(float4*)&LB[r * SP + c] = *(const float4*)(R + e);
  }
  __syncthreads();
  const int n = tid & 63, q = tid >> 6;
  float arow[64];
#pragma unroll
  for (int mm = 0; mm < 16; ++mm) {
    const float4 a4 = *(const float4*)(LA + n * SP + mm * 4);
    arow[4 * mm + 0] = a4.x; arow[4 * mm + 1] = a4.y;
    arow[4 * mm + 2] = a4.z; arow[4 * mm + 3] = a4.w;
  }
  float acc[16];
#pragma unroll
  for (int i = 0; i < 16; ++i) acc[i] = 0.f;
#pragma unroll 8
  for (int m = 0; m < 64; ++m) {
    const float4 b0 = *(const float4*)(LB + m * SP + q * 16 + 0);
    const float4 b1 = *(const float4*)(LB + m * SP + q * 16 + 4);
    const float4 b2 = *(const float4*)(LB + m * SP + q * 16 + 8);
    const float4 b3 = *(const float4*)(LB + m * SP + q * 16 + 12);
    const float a = arow[m];
    acc[0]  = fmaf(a, b0.x, acc[0]);  acc[1]  = fmaf(a, b0.y, acc[1]);
    acc[2]  = fmaf(a, b0.z, acc[2]);  acc[3]  = fmaf(a, b0.w, acc[3]);
    acc[4]  = fmaf(a, b1.x, acc[4]);  acc[5]  = fmaf(a, b1.y, acc[5]);
    acc[6]  = fmaf(a, b1.z, acc[6]);  acc[7]  = fmaf(a, b1.w, acc[7]);
    acc[8]  = fmaf(a, b2.x, acc[8]);  acc[9]  = fmaf(a, b2.y, acc[9]);
    acc[10] = fmaf(a, b2.z, acc[10]); acc[11] = fmaf(a, b2.w, acc[11]);
    acc[12] = fmaf(a, b3.x, acc[12]); acc[13] = fmaf(a, b3.y, acc[13]);
    acc[14] = fmaf(a, b3.z, acc[14]); acc[15] = fmaf(a, b3.w, acc[15]);
  }
#pragma unroll
  for (int v = 0; v < 4; ++v) {
    float4 o;
    o.x = acc[4 * v + 0]; o.y = acc[4 * v + 1];
    o.z = acc[4 * v + 2]; o.w = acc[4 * v + 3];
    *(float4*)(O + n * 64 + q * 16 + 4 * v) = o;
  }
}

// ---- per-d build: chained matvecs on shared A, emit small vectors ----
__global__ __launch_bounds__(256, 1) void s4_build2(
    const float* __restrict__ Apow, const float* __restrict__ Bp,
    const float* __restrict__ Cp, const float* __restrict__ log_delta,
    float* __restrict__ Gk, float* __restrict__ Qk,
    float* __restrict__ kloc, float* __restrict__ dts) {
  __shared__ float As[Nz * SA];
  __shared__ float Pst[KP + 1][Nz];
  __shared__ float Qst[KE + 1][Nz];
  __shared__ float Pv[Nz], Qv[Nz], dBs[Nz];
  __shared__ float prA[4][Nz + 8], prB[4][Nz + 8];
  __shared__ float zp[KE + 1][17], zs[KE + 1];
  const int tid = threadIdx.x;
  const int d = blockIdx.x;
  const int n = tid & 63, qq = tid >> 6;
  const float dt = softplusf(log_delta[d]) + 1e-6f;

#pragma unroll
  for (int i = 0; i < 4; ++i) {
    const int e = (tid + 256 * i) * 4;
    const int r = e >> 6, c = e & 63;
    const float4 v = *(const float4*)(Apow + e);
    As[r * SA + c] = v.x; As[r * SA + c + 1] = v.y;
    As[r * SA + c + 2] = v.z; As[r * SA + c + 3] = v.w;
  }
  if (tid < 64) {
    const float bv = Bp[d * Nz + tid], cv = Cp[d * Nz + tid];
    Pv[tid] = bv; Pst[0][tid] = bv;
    Qv[tid] = cv; Qst[0][tid] = cv;
  }
  __syncthreads();
#pragma unroll 1
  for (int k = 1; k <= KP; ++k) {
    float pp = 0.f, pq = 0.f;
#pragma unroll
    for (int mm = 0; mm < 16; ++mm) {
      const int m = qq * 16 + mm;
      pp += As[n * SA + m] * Pv[m];   // (A p)[n]
      pq += As[m * SA + n] * Qv[m];   // (A^T q)[n]
    }
    prA[qq][n] = pp; prB[qq][n] = pq;
    __syncthreads();
    if (tid < 64) {
      const float np = prA[0][tid] + prA[1][tid] + prA[2][tid] + prA[3][tid];
      Pv[tid] = np; Pst[k][tid] = np;
      if (k <= KE) {
        const float nq = prB[0][tid] + prB[1][tid] + prB[2][tid] + prB[3][tid];
        Qv[tid] = nq; Qst[k][tid] = nq;
      }
    }
    __syncthreads();
  }
  const float dtc0 = dt;
  const float dtc1 = dt * dt * 0.5f;
  const float dtc2 = dtc1 * dt * (1.f / 3.f);
  const float dtc3 = dtc2 * dt * 0.25f;
  if (tid < 64) {
    dBs[tid] = dtc0 * Pst[0][tid] + dtc1 * Pst[1][tid] +
               dtc2 * Pst[2][tid] + dtc3 * Pst[3][tid];
#pragma unroll
    for (int k = 0; k <= KE; ++k) {
      Gk[(size_t)d * ((KE + 1) * 64) + k * 64 + tid] =
          dtc0 * Pst[k][tid] + dtc1 * Pst[k + 1][tid] +
          dtc2 * Pst[k + 2][tid] + dtc3 * Pst[k + 3][tid];
      Qk[(size_t)d * ((KE + 1) * 64) + k * 64 + tid] = Qst[k][tid];
    }
  }
  __syncthreads();
  if (tid < (KE + 1) * 16) {
    const int k = tid >> 4, seg = tid & 15;
    float s = 0.f;
#pragma unroll
    for (int i = 0; i < 4; ++i) s += Qst[k][seg * 4 + i] * dBs[seg * 4 + i];
    zp[k][seg] = s;
  }
  __syncthreads();
  if (tid <= KE) {
    float s = 0.f;
#pragma unroll
    for (int seg = 0; seg < 16; ++seg) s += zp[tid][seg];
    zs[tid] = s;
  }
  __syncthreads();
  if (tid < 64) {
    const float rdt = (float)tid * dt;
    float c = 1.f, acc = zs[0];
#pragma unroll
    for (int k = 1; k <= KE; ++k) { c *= rdt / (float)k; acc += c * zs[k]; }
    kloc[d * 64 + tid] = acc;
  }
  if (tid == 0) dts[d] = dt;
}

// Chunked state scan v4. Grid (Dz, BSP=4): 1024 blocks = 4/CU. Block handles
// BPB=2 batches of one d. Dot products split across 4 wave-groups; thread
// (n,q) holds Er[16], Ur[16] (constant-indexed, never spilled).
__global__ __launch_bounds__(256) void s4_scan4(
    const float* __restrict__ xT, const float* __restrict__ Apow,
    const float* __restrict__ Gk, const float* __restrict__ dts,
    float* __restrict__ S) {
  __shared__ float Es[Nz * SA];
  __shared__ float Gs[(KE + 1) * Nz];
  __shared__ float CTs[KE + 1][66];
  __shared__ alignas(16) float Xs[BPB][64];
  __shared__ alignas(16) float Ss[BPB][64];
  __shared__ float pr[4][BPB][64];
  const int d = blockIdx.x;
  const int z = blockIdx.y;
  const int tid = threadIdx.x, n = tid & 63, q = tid >> 6;
  const int rb = tid >> 6;               // staging/reduce ownership (rb < BPB)
  const float dt = dts[d];
  if (tid < 65) {
    const float rdt = (float)tid * dt;
    float c = 1.f;
    CTs[0][tid] = 1.f;
#pragma unroll
    for (int k = 1; k <= KE; ++k) { c *= rdt / (float)k; CTs[k][tid] = c; }
  }
  for (int idx = tid; idx < (KE + 1) * 64; idx += 256)
    Gs[idx] = Gk[(size_t)d * ((KE + 1) * 64) + idx];
  // E64 (incl identity) into LDS; each thread owns 16 elements.
  {
    float ea[16];
#pragma unroll
    for (int i = 0; i < 16; ++i) ea[i] = 0.f;
    const float dt64 = 64.f * dt;
    float ce = 1.f;
#pragma unroll 1
    for (int k = 1; k <= KE; ++k) {
      ce *= dt64 / (float)k;
      const float* Ak = Apow + (size_t)(k - 1) * 4096;
#pragma unroll
      for (int i = 0; i < 16; ++i)
        ea[i] = fmaf(ce, Ak[tid + 256 * i], ea[i]);
    }
#pragma unroll
    for (int i = 0; i < 16; ++i) {
      const int e = tid + 256 * i;
      const int r = e >> 6, c = e & 63;
      Es[r * SA + c] = ea[i] + ((r == c) ? 1.f : 0.f);
    }
  }
  __syncthreads();
  float Er[16], Ur[16];
#pragma unroll
  for (int i = 0; i < 16; ++i) Er[i] = Es[n * SA + q * 16 + i];
#pragma unroll
  for (int i = 0; i < 16; ++i) {
    const int j = q * 16 + i;
    float u = 0.f;
#pragma unroll
    for (int k = 0; k <= KE; ++k) u = fmaf(CTs[k][63 - j], Gs[k * 64 + n], u);
    Ur[i] = u;                    // = Uf[n][j] = (E^{63-j} dB)[n]
  }
  if (rb < BPB) Ss[rb][n] = 0.f;
  const float* xd = xT + ((size_t)d * Bz + z * BPB) * Lz;
  float* Sd = S + (size_t)d * (32 * 8 * 64) + (size_t)(z * BPB) * 64;
#pragma unroll 1
  for (int c = 0; c < 32; ++c) {
    if (rb < BPB) {
      Xs[rb][n] = xd[(size_t)rb * Lz + c * 64 + n];
      Sd[c * 512 + rb * 64 + n] = Ss[rb][n];   // state entering chunk c
    }
    __syncthreads();                            // B1: Xs/Ss ready
    float acc[BPB];
#pragma unroll
    for (int b = 0; b < BPB; ++b) {
      const float4 s0 = *(const float4*)&Ss[b][q * 16 + 0];
      const float4 s1 = *(const float4*)&Ss[b][q * 16 + 4];
      const float4 s2 = *(const float4*)&Ss[b][q * 16 + 8];
      const float4 s3 = *(const float4*)&Ss[b][q * 16 + 12];
      const float4 x0 = *(const float4*)&Xs[b][q * 16 + 0];
      const float4 x1 = *(const float4*)&Xs[b][q * 16 + 4];
      const float4 x2 = *(const float4*)&Xs[b][q * 16 + 8];
      const float4 x3 = *(const float4*)&Xs[b][q * 16 + 12];
      float a = 0.f;
      a = fmaf(Er[0], s0.x, a);  a = fmaf(Er[1], s0.y, a);
      a = fmaf(Er[2], s0.z, a);  a = fmaf(Er[3], s0.w, a);
      a = fmaf(Er[4], s1.x, a);  a = fmaf(Er[5], s1.y, a);
      a = fmaf(Er[6], s1.z, a);  a = fmaf(Er[7], s1.w, a);
      a = fmaf(Er[8], s2.x, a);  a = fmaf(Er[9], s2.y, a);
      a = fmaf(Er[10], s2.z, a); a = fmaf(Er[11], s2.w, a);
      a = fmaf(Er[12], s3.x, a); a = fmaf(Er[13], s3.y, a);
      a = fmaf(Er[14], s3.z, a); a = fmaf(Er[15], s3.w, a);
      a = fmaf(Ur[0], x0.x, a);  a = fmaf(Ur[1], x0.y, a);
      a = fmaf(Ur[2], x0.z, a);  a = fmaf(Ur[3], x0.w, a);
      a = fmaf(Ur[4], x1.x, a);  a = fmaf(Ur[5], x1.y, a);
      a = fmaf(Ur[6], x1.z, a);  a = fmaf(Ur[7], x1.w, a);
      a = fmaf(Ur[8], x2.x, a);  a = fmaf(Ur[9], x2.y, a);
      a = fmaf(Ur[10], x2.z, a); a = fmaf(Ur[11], x2.w, a);
      a = fmaf(Ur[12], x3.x, a); a = fmaf(Ur[13], x3.y, a);
      a = fmaf(Ur[14], x3.z, a); a = fmaf(Ur[15], x3.w, a);
      acc[b] = a;
    }
#pragma unroll
    for (int b = 0; b < BPB; ++b) pr[q][b][n] = acc[b];
    __syncthreads();                            // B2: pr ready
    if (rb < BPB)
      Ss[rb][n] = pr[0][rb][n] + pr[1][rb][n] + pr[2][rb][n] + pr[3][rb][n];
    __syncthreads();                            // B3: Ss updated
  }
}

// Output as LDS-tiled GEMM, split 2 blocks/d (grid (Dz,2), 512 = 2/CU).
// per d:  y(64 x 256) = [W|T](64 x 128) . [S;X](128 x 256), 2 col-chunks/block.
__global__ __launch_bounds__(256, 2) void s4_out4(
    const float* __restrict__ xT, const float* __restrict__ S,
    const float* __restrict__ Qk, const float* __restrict__ kloc,
    const float* __restrict__ dts, float* __restrict__ yT) {
  __shared__ alignas(16) float Ms[64 * SM];   // [r][k]  k<64: W, k>=64: T
  __shared__ alignas(16) float Zs[64 * SM];   // [col][k] k<64: S, k>=64: X
  __shared__ float Qs[(KE + 1) * Nz];
  __shared__ float CT[KE + 1][66];
  __shared__ float kx[64];
  const int d = blockIdx.x;
  const int tid = threadIdx.x;
  const int tc = tid & 15, tr = tid >> 4;
  const float dt = dts[d];
  if (tid < 65) {
    const float rdt = (float)tid * dt;
    float c = 1.f;
    CT[0][tid] = 1.f;
#pragma unroll
    for (int k = 1; k <= KE; ++k) { c *= rdt / (float)k; CT[k][tid] = c; }
  }
  for (int idx = tid; idx < (KE + 1) * 64; idx += 256)
    Qs[idx] = Qk[(size_t)d * ((KE + 1) * 64) + idx];
  if (tid < 64) kx[tid] = kloc[d * 64 + tid];
  __syncthreads();
#pragma unroll
  for (int i = 0; i < 16; ++i) {
    const int e = tid + 256 * i;
    const int r = e >> 6, m = e & 63;
    float w = 0.f;
#pragma unroll
    for (int k = 0; k <= KE; ++k) w = fmaf(CT[k][r + 1], Qs[k * 64 + m], w);
    Ms[r * SM + m] = w;
  }
#pragma unroll
  for (int i = 0; i < 16; ++i) {
    const int e = tid + 256 * i;
    const int r = e >> 6, j = e & 63;
    Ms[r * SM + 64 + j] = (j <= r) ? kx[r - j] : 0.f;
  }
  const float* xd = xT + (size_t)d * Bz * Lz;
  const float* Sd = S + (size_t)d * (32 * 8 * 64);
  float* yd = yT + (size_t)d * Bz * Lz;
  const int lcol = tid >> 2, seg = tid & 3;
  const int sbb = lcol & 7, sccl = lcol >> 3;
#pragma unroll 1
  for (int it = 0; it < 2; ++it) {
    const int ch = blockIdx.y * 2 + it;
    {
      const int cc = ch * 8 + sccl;
      const float* sp = Sd + cc * 512 + sbb * 64 + seg * 16;
      const float* xp = xd + (size_t)sbb * Lz + cc * 64 + seg * 16;
      float* zrow = Zs + lcol * SM;
#pragma unroll
      for (int i = 0; i < 4; ++i) {
        *(float4*)(zrow + seg * 16 + i * 4) = *(const float4*)(sp + i * 4);
        *(float4*)(zrow + 64 + seg * 16 + i * 4) = *(const float4*)(xp + i * 4);
      }
    }
    __syncthreads();
    float acc[16];
#pragma unroll
    for (int i = 0; i < 16; ++i) acc[i] = 0.f;
#pragma unroll 4
    for (int k = 0; k < 128; k += 4) {
      float4 mv[4], zv[4];
#pragma unroll
      for (int i = 0; i < 4; ++i)
        mv[i] = *(const float4*)&Ms[(tr * 4 + i) * SM + k];
#pragma unroll
      for (int jj = 0; jj < 4; ++jj)
        zv[jj] = *(const float4*)&Zs[(tc + 16 * jj) * SM + k];
#pragma unroll
      for (int i = 0; i < 4; ++i)
#pragma unroll
        for (int jj = 0; jj < 4; ++jj) {
          acc[i * 4 + jj] = fmaf(mv[i].x, zv[jj].x, acc[i * 4 + jj]);
          acc[i * 4 + jj] = fmaf(mv[i].y, zv[jj].y, acc[i * 4 + jj]);
          acc[i * 4 + jj] = fmaf(mv[i].z, zv[jj].z, acc[i * 4 + jj]);
          acc[i * 4 + jj] = fmaf(mv[i].w, zv[jj].w, acc[i * 4 + jj]);
        }
    }
    __syncthreads();
#pragma unroll
    for (int i = 0; i < 4; ++i)
#pragma unroll
      for (int jj = 0; jj < 4; ++jj)
        Zs[(tc + 16 * jj) * SM + tr * 4 + i] = acc[i * 4 + jj];
    __syncthreads();
    {
      const int cc = ch * 8 + sccl;
      float* yp = yd + (size_t)sbb * Lz + cc * 64 + seg * 16;
      const float* zrow = Zs + lcol * SM;
#pragma unroll
      for (int i = 0; i < 4; ++i)
        *(float4*)(yp + i * 4) = *(const float4*)(zrow + seg * 16 + i * 4);
    }
    __syncthreads();
  }
}

// Final GEMM v3: 128x64 tile, 8x4 microtile, grid 512 = 2 blocks/CU.
__global__ __launch_bounds__(256, 2) void s4_gemm3(
    const float* __restrict__ yT, const float* __restrict__ xT,
    const float* __restrict__ skip_D, const float* __restrict__ Wo,
    const float* __restrict__ bo, float* __restrict__ out) {
  __shared__ alignas(16) float Ys2[16 * SG];   // [dk][row 0..127]
  __shared__ float Ws2[16 * SW];               // [dk][col 0..63]
  const int tid = threadIdx.x;
  const int r0 = blockIdx.x * 128;
  const int c0 = blockIdx.y * 64;
  const int brow = r0 >> 11;
  const int t0 = r0 & 2047;
  const int tr = tid >> 4, tc = tid & 15;
  const int ytt = tid & 127, ydh = tid >> 7;
  const int wr = tid >> 2, wq = tid & 3;
  float acc[32];
#pragma unroll
  for (int i = 0; i < 32; ++i) acc[i] = 0.f;
#pragma unroll 1
  for (int kc = 0; kc < 16; ++kc) {
    const int dc0 = kc * 16;
#pragma unroll
    for (int p = 0; p < 8; ++p) {
      const int dk = p * 2 + ydh;
      const int dd = dc0 + dk;
      const size_t off = ((size_t)dd * Bz + brow) * Lz + t0 + ytt;
      Ys2[dk * SG + ytt] = yT[off] + xT[off] * skip_D[dd];
    }
    {
      const float4 w4 = *(const float4*)(Wo + (size_t)(c0 + wr) * Dz + dc0 + wq * 4);
      Ws2[(wq * 4 + 0) * SW + wr] = w4.x;
      Ws2[(wq * 4 + 1) * SW + wr] = w4.y;
      Ws2[(wq * 4 + 2) * SW + wr] = w4.z;
      Ws2[(wq * 4 + 3) * SW + wr] = w4.w;
    }
    __syncthreads();
#pragma unroll
    for (int dk = 0; dk < 16; ++dk) {
      const float4 a0 = *(const float4*)&Ys2[dk * SG + tr * 8];
      const float4 a1 = *(const float4*)&Ys2[dk * SG + tr * 8 + 4];
      float bv[4];
#pragma unroll
      for (int jj = 0; jj < 4; ++jj) bv[jj] = Ws2[dk * SW + tc + 16 * jj];
#pragma unroll
      for (int jj = 0; jj < 4; ++jj) {
        acc[0 * 4 + jj] = fmaf(a0.x, bv[jj], acc[0 * 4 + jj]);
        acc[1 * 4 + jj] = fmaf(a0.y, bv[jj], acc[1 * 4 + jj]);
        acc[2 * 4 + jj] = fmaf(a0.z, bv[jj], acc[2 * 4 + jj]);
        acc[3 * 4 + jj] = fmaf(a0.w, bv[jj], acc[3 * 4 + jj]);
        acc[4 * 4 + jj] = fmaf(a1.x, bv[jj], acc[4 * 4 + jj]);
        acc[5 * 4 + jj] = fmaf(a1.y, bv[jj], acc[5 * 4 + jj]);
        acc[6 * 4 + jj] = fmaf(a1.z, bv[jj], acc[6 * 4 + jj]);
        acc[7 * 4 + jj] = fmaf(a1.w, bv[jj], acc[7 * 4 + jj]);
      }
    }
    __syncthreads();
  }
  float bb[4];
#pragma unroll
  for (int jj = 0; jj < 4; ++jj) bb[jj] = bo[c0 + tc + 16 * jj];
#pragma unroll
  for (int i = 0; i < 8; ++i) {
    float* op = out + (size_t)(r0 + tr * 8 + i) * Dz + c0 + tc;
#pragma unroll
    for (int jj = 0; jj < 4; ++jj)
      op[16 * jj] = acc[i * 4 + jj] + bb[jj];
  }
}

extern "C" void kernel_launch(void* const* d_in, const int* in_sizes, int n_in,
                              void* d_out, int out_size, void* d_ws, size_t ws_size,
                              hipStream_t stream) {
  const float* x         = (const float*)d_in[0];
  const float* log_A     = (const float*)d_in[1];
  const float* Bp        = (const float*)d_in[2];
  const float* Cp        = (const float*)d_in[3];
  const float* log_delta = (const float*)d_in[4];
  const float* skip_D    = (const float*)d_in[5];
  const float* W_out     = (const float*)d_in[6];
  const float* b_out     = (const float*)d_in[7];
  float* out = (float*)d_out;

  float* xT   = (float*)d_ws;
  float* yT   = xT + (size_t)Dz * Bz * Lz;
  float* S    = yT + (size_t)Dz * Bz * Lz;
  float* Apow = S + (size_t)Dz * (32 * 8 * 64);
  float* Gk   = Apow + (size_t)8 * 4096;
  float* Qk   = Gk + (size_t)Dz * (KE + 1) * 64;
  float* kloc = Qk + (size_t)Dz * (KE + 1) * 64;
  float* dts  = kloc + (size_t)Dz * 64;

  hipLaunchKernelGGL(s4_xt, dim3(Lz / 64, Dz / 64, Bz), dim3(256), 0, stream,
                     x, xT, log_A, Apow);
  hipLaunchKernelGGL(s4_powmm, dim3(1), dim3(256), 0, stream, Apow, Apow, 0, 1);
  hipLaunchKernelGGL(s4_powmm, dim3(2), dim3(256), 0, stream, Apow, Apow, 1, 2);
  hipLaunchKernelGGL(s4_build2, dim3(Dz), dim3(256), 0, stream,
                     Apow, Bp, Cp, log_delta, Gk, Qk, kloc, dts);
  hipLaunchKernelGGL(s4_scan4, dim3(Dz, BSP), dim3(256), 0, stream,
                     xT, Apow, Gk, dts, S);
  hipLaunchKernelGGL(s4_out4, dim3(Dz, 2), dim3(256), 0, stream,
                     xT, S, Qk, kloc, dts, yT);
  hipLaunchKernelGGL(s4_gemm3, dim3((Bz * Lz) / 128, Dz / 64), dim3(256), 0, stream,
                     yT, xT, skip_D, W_out, b_out, out);
}

// Round 13
// 192.659 us; speedup vs baseline: 1.3865x; 1.0267x over previous
//
#include <hip/hip_runtime.h>

#define Bz 8
#define Lz 2048
#define Dz 256
#define Nz 64
#define SP 68   // b128-aligned LDS stride (power matmuls)
#define SA 65   // scalar-access LDS stride (conflict-free rows+cols)
#define SM 132  // out5 LDS stride
#define SG 136  // gemm3 Ys stride (16B-aligned rows)
#define SW 73   // gemm3 Ws stride (odd -> conflict-free transposed writes)
#define KE 4    // Taylor order: ||64*dt*A|| <= ~0.15 -> rel err ~6e-7
#define KP 7    // p-chain depth = KE + 3 (dB phi1 terms)
#define BSP 4   // scan: blocks per channel (batch split)
#define BPB (Bz / BSP)   // 2 batches per block

__device__ __forceinline__ float softplusf(float x) {
  return (x > 20.f) ? x : log1pf(expf(x));
}

// acc = row n of (LA * LB), cols q*16..q*16+15 (SP strides). No barriers.
__device__ __forceinline__ void pmm_acc(const float* __restrict__ LA,
                                        const float* __restrict__ LB,
                                        float* acc, int n, int q) {
  float arow[64];
#pragma unroll
  for (int mm = 0; mm < 16; ++mm) {
    const float4 a4 = *(const float4*)(LA + n * SP + mm * 4);
    arow[4 * mm + 0] = a4.x; arow[4 * mm + 1] = a4.y;
    arow[4 * mm + 2] = a4.z; arow[4 * mm + 3] = a4.w;
  }
#pragma unroll
  for (int i = 0; i < 16; ++i) acc[i] = 0.f;
#pragma unroll 8
  for (int m = 0; m < 64; ++m) {
    const float4 b0 = *(const float4*)(LB + m * SP + q * 16 + 0);
    const float4 b1 = *(const float4*)(LB + m * SP + q * 16 + 4);
    const float4 b2 = *(const float4*)(LB + m * SP + q * 16 + 8);
    const float4 b3 = *(const float4*)(LB + m * SP + q * 16 + 12);
    const float a = arow[m];
    acc[0]  = fmaf(a, b0.x, acc[0]);  acc[1]  = fmaf(a, b0.y, acc[1]);
    acc[2]  = fmaf(a, b0.z, acc[2]);  acc[3]  = fmaf(a, b0.w, acc[3]);
    acc[4]  = fmaf(a, b1.x, acc[4]);  acc[5]  = fmaf(a, b1.y, acc[5]);
    acc[6]  = fmaf(a, b1.z, acc[6]);  acc[7]  = fmaf(a, b1.w, acc[7]);
    acc[8]  = fmaf(a, b2.x, acc[8]);  acc[9]  = fmaf(a, b2.y, acc[9]);
    acc[10] = fmaf(a, b2.z, acc[10]); acc[11] = fmaf(a, b2.w, acc[11]);
    acc[12] = fmaf(a, b3.x, acc[12]); acc[13] = fmaf(a, b3.y, acc[13]);
    acc[14] = fmaf(a, b3.z, acc[14]); acc[15] = fmaf(a, b3.w, acc[15]);
  }
}

// ---- Transpose x[b][t][d] -> xT[d][b][t] (float4 both sides);
//      folds powinit (Apow[0] = softplus(log_A)). ----
__global__ __launch_bounds__(256) void s4_xt(const float* __restrict__ x,
                                             float* __restrict__ xT,
                                             const float* __restrict__ log_A,
                                             float* __restrict__ Apow) {
  if (blockIdx.x == 0 && blockIdx.y == 0) {
    const int i = blockIdx.z * 512 + threadIdx.x;
    Apow[i] = softplusf(log_A[i]);
    Apow[i + 256] = softplusf(log_A[i + 256]);
  }
  __shared__ float tile[64][69];   // stride 69: column reads are 2-way (free)
  const int t0 = blockIdx.x * 64, d0 = blockIdx.y * 64, b = blockIdx.z;
  const int rr = threadIdx.x >> 4;          // 0..15
  const int c4 = (threadIdx.x & 15) * 4;    // 0..60
#pragma unroll
  for (int p = 0; p < 4; ++p) {
    const int row = p * 16 + rr;            // t within tile
    const float4 v = *(const float4*)(x + ((size_t)b * Lz + t0 + row) * Dz + d0 + c4);
    tile[row][c4 + 0] = v.x; tile[row][c4 + 1] = v.y;
    tile[row][c4 + 2] = v.z; tile[row][c4 + 3] = v.w;
  }
  __syncthreads();
#pragma unroll
  for (int p = 0; p < 4; ++p) {
    const int dd = p * 16 + rr;             // d within tile
    float4 o;
    o.x = tile[c4 + 0][dd]; o.y = tile[c4 + 1][dd];
    o.z = tile[c4 + 2][dd]; o.w = tile[c4 + 3][dd];
    *(float4*)(xT + ((size_t)(d0 + dd) * Bz + b) * Lz + t0 + c4) = o;
  }
}

// ---- fused build + power-basis: blocks 0..255 per-d chains; blocks
//      256..258 compute A2 / A3 / A4 (fold of the two old powmm launches) ----
__global__ __launch_bounds__(256, 1) void s4_buildpow(
    float* __restrict__ Apow, const float* __restrict__ Bp,
    const float* __restrict__ Cp, const float* __restrict__ log_delta,
    float* __restrict__ Gk, float* __restrict__ Qk,
    float* __restrict__ kloc, float* __restrict__ dts) {
  __shared__ float As[Nz * SA];
  __shared__ float Pst[KP + 1][Nz];
  __shared__ float Qst[KE + 1][Nz];
  __shared__ float Pv[Nz], Qv[Nz], dBs[Nz];
  __shared__ float prA[4][Nz + 8], prB[4][Nz + 8];
  __shared__ float zp[KE + 1][17], zs[KE + 1];
  __shared__ alignas(16) float PA[Nz * SP];
  __shared__ alignas(16) float PB[Nz * SP];
  const int tid = threadIdx.x;
  const int d = blockIdx.x;
  const int n = tid & 63, qq = tid >> 6;

  if (d >= Dz) {
    // power blocks: role 0 -> A2, 1 -> A3 = A*A2, 2 -> A4 = A2*A2
    const int role = d - Dz;
#pragma unroll
    for (int i = 0; i < 4; ++i) {
      const int e = (tid + 256 * i) * 4;
      const int r = e >> 6, c = e & 63;
      const float4 v = *(const float4*)(Apow + e);
      *(float4*)&PA[r * SP + c] = v;
      *(float4*)&PB[r * SP + c] = v;
    }
    __syncthreads();
    float acc[16];
    pmm_acc(PA, PB, acc, n, qq);       // acc = A*A = A2 (row n, cols qq*16..)
    if (role == 0) {
      float* O = Apow + (size_t)1 * 4096;
#pragma unroll
      for (int v = 0; v < 4; ++v) {
        float4 o;
        o.x = acc[4 * v]; o.y = acc[4 * v + 1];
        o.z = acc[4 * v + 2]; o.w = acc[4 * v + 3];
        *(float4*)(O + n * 64 + qq * 16 + 4 * v) = o;
      }
      return;
    }
    __syncthreads();                   // all A2 reads done
#pragma unroll
    for (int i = 0; i < 16; ++i) {
      PB[n * SP + qq * 16 + i] = acc[i];
      if (role == 2) PA[n * SP + qq * 16 + i] = acc[i];
    }
    __syncthreads();
    pmm_acc(PA, PB, acc, n, qq);       // role1: A*A2 ; role2: A2*A2
    float* O = Apow + (size_t)(role + 1) * 4096;
#pragma unroll
    for (int v = 0; v < 4; ++v) {
      float4 o;
      o.x = acc[4 * v]; o.y = acc[4 * v + 1];
      o.z = acc[4 * v + 2]; o.w = acc[4 * v + 3];
      *(float4*)(O + n * 64 + qq * 16 + 4 * v) = o;
    }
    return;
  }

  const float dt = softplusf(log_delta[d]) + 1e-6f;
#pragma unroll
  for (int i = 0; i < 4; ++i) {
    const int e = (tid + 256 * i) * 4;
    const int r = e >> 6, c = e & 63;
    const float4 v = *(const float4*)(Apow + e);
    As[r * SA + c] = v.x; As[r * SA + c + 1] = v.y;
    As[r * SA + c + 2] = v.z; As[r * SA + c + 3] = v.w;
  }
  if (tid < 64) {
    const float bv = Bp[d * Nz + tid], cv = Cp[d * Nz + tid];
    Pv[tid] = bv; Pst[0][tid] = bv;
    Qv[tid] = cv; Qst[0][tid] = cv;
  }
  __syncthreads();
#pragma unroll 1
  for (int k = 1; k <= KP; ++k) {
    float pp = 0.f, pq = 0.f;
#pragma unroll
    for (int mm = 0; mm < 16; ++mm) {
      const int m = qq * 16 + mm;
      pp += As[n * SA + m] * Pv[m];   // (A p)[n]
      pq += As[m * SA + n] * Qv[m];   // (A^T q)[n]
    }
    prA[qq][n] = pp; prB[qq][n] = pq;
    __syncthreads();
    if (tid < 64) {
      const float np = prA[0][tid] + prA[1][tid] + prA[2][tid] + prA[3][tid];
      Pv[tid] = np; Pst[k][tid] = np;
      if (k <= KE) {
        const float nq = prB[0][tid] + prB[1][tid] + prB[2][tid] + prB[3][tid];
        Qv[tid] = nq; Qst[k][tid] = nq;
      }
    }
    __syncthreads();
  }
  const float dtc0 = dt;
  const float dtc1 = dt * dt * 0.5f;
  const float dtc2 = dtc1 * dt * (1.f / 3.f);
  const float dtc3 = dtc2 * dt * 0.25f;
  if (tid < 64) {
    dBs[tid] = dtc0 * Pst[0][tid] + dtc1 * Pst[1][tid] +
               dtc2 * Pst[2][tid] + dtc3 * Pst[3][tid];
#pragma unroll
    for (int k = 0; k <= KE; ++k) {
      Gk[(size_t)d * ((KE + 1) * 64) + k * 64 + tid] =
          dtc0 * Pst[k][tid] + dtc1 * Pst[k + 1][tid] +
          dtc2 * Pst[k + 2][tid] + dtc3 * Pst[k + 3][tid];
      Qk[(size_t)d * ((KE + 1) * 64) + k * 64 + tid] = Qst[k][tid];
    }
  }
  __syncthreads();
  if (tid < (KE + 1) * 16) {
    const int k = tid >> 4, seg = tid & 15;
    float s = 0.f;
#pragma unroll
    for (int i = 0; i < 4; ++i) s += Qst[k][seg * 4 + i] * dBs[seg * 4 + i];
    zp[k][seg] = s;
  }
  __syncthreads();
  if (tid <= KE) {
    float s = 0.f;
#pragma unroll
    for (int seg = 0; seg < 16; ++seg) s += zp[tid][seg];
    zs[tid] = s;
  }
  __syncthreads();
  if (tid < 64) {
    const float rdt = (float)tid * dt;
    float c = 1.f, acc = zs[0];
#pragma unroll
    for (int k = 1; k <= KE; ++k) { c *= rdt / (float)k; acc += c * zs[k]; }
    kloc[d * 64 + tid] = acc;
  }
  if (tid == 0) dts[d] = dt;
}

// Chunked state scan v4. Grid (Dz, BSP=4): 1024 blocks = 4/CU. Block handles
// BPB=2 batches of one d. Thread (n,q) holds Er[16], Ur[16] (constant-indexed).
__global__ __launch_bounds__(256) void s4_scan4(
    const float* __restrict__ xT, const float* __restrict__ Apow,
    const float* __restrict__ Gk, const float* __restrict__ dts,
    float* __restrict__ S) {
  __shared__ float Es[Nz * SA];
  __shared__ float Gs[(KE + 1) * Nz];
  __shared__ float CTs[KE + 1][66];
  __shared__ alignas(16) float Xs[BPB][64];
  __shared__ alignas(16) float Ss[BPB][64];
  __shared__ float pr[4][BPB][64];
  const int d = blockIdx.x;
  const int z = blockIdx.y;
  const int tid = threadIdx.x, n = tid & 63, q = tid >> 6;
  const int rb = tid >> 6;               // staging/reduce ownership (rb < BPB)
  const float dt = dts[d];
  if (tid < 65) {
    const float rdt = (float)tid * dt;
    float c = 1.f;
    CTs[0][tid] = 1.f;
#pragma unroll
    for (int k = 1; k <= KE; ++k) { c *= rdt / (float)k; CTs[k][tid] = c; }
  }
  for (int idx = tid; idx < (KE + 1) * 64; idx += 256)
    Gs[idx] = Gk[(size_t)d * ((KE + 1) * 64) + idx];
  {
    float ea[16];
#pragma unroll
    for (int i = 0; i < 16; ++i) ea[i] = 0.f;
    const float dt64 = 64.f * dt;
    float ce = 1.f;
#pragma unroll 1
    for (int k = 1; k <= KE; ++k) {
      ce *= dt64 / (float)k;
      const float* Ak = Apow + (size_t)(k - 1) * 4096;
#pragma unroll
      for (int i = 0; i < 16; ++i)
        ea[i] = fmaf(ce, Ak[tid + 256 * i], ea[i]);
    }
#pragma unroll
    for (int i = 0; i < 16; ++i) {
      const int e = tid + 256 * i;
      const int r = e >> 6, c = e & 63;
      Es[r * SA + c] = ea[i] + ((r == c) ? 1.f : 0.f);
    }
  }
  __syncthreads();
  float Er[16], Ur[16];
#pragma unroll
  for (int i = 0; i < 16; ++i) Er[i] = Es[n * SA + q * 16 + i];
#pragma unroll
  for (int i = 0; i < 16; ++i) {
    const int j = q * 16 + i;
    float u = 0.f;
#pragma unroll
    for (int k = 0; k <= KE; ++k) u = fmaf(CTs[k][63 - j], Gs[k * 64 + n], u);
    Ur[i] = u;                    // = Uf[n][j] = (E^{63-j} dB)[n]
  }
  if (rb < BPB) Ss[rb][n] = 0.f;
  const float* xd = xT + ((size_t)d * Bz + z * BPB) * Lz;
  float* Sd = S + (size_t)d * (32 * 8 * 64) + (size_t)(z * BPB) * 64;
#pragma unroll 1
  for (int c = 0; c < 32; ++c) {
    if (rb < BPB) {
      Xs[rb][n] = xd[(size_t)rb * Lz + c * 64 + n];
      Sd[c * 512 + rb * 64 + n] = Ss[rb][n];   // state entering chunk c
    }
    __syncthreads();                            // B1: Xs/Ss ready
    float acc[BPB];
#pragma unroll
    for (int b = 0; b < BPB; ++b) {
      const float4 s0 = *(const float4*)&Ss[b][q * 16 + 0];
      const float4 s1 = *(const float4*)&Ss[b][q * 16 + 4];
      const float4 s2 = *(const float4*)&Ss[b][q * 16 + 8];
      const float4 s3 = *(const float4*)&Ss[b][q * 16 + 12];
      const float4 x0 = *(const float4*)&Xs[b][q * 16 + 0];
      const float4 x1 = *(const float4*)&Xs[b][q * 16 + 4];
      const float4 x2 = *(const float4*)&Xs[b][q * 16 + 8];
      const float4 x3 = *(const float4*)&Xs[b][q * 16 + 12];
      float a = 0.f;
      a = fmaf(Er[0], s0.x, a);  a = fmaf(Er[1], s0.y, a);
      a = fmaf(Er[2], s0.z, a);  a = fmaf(Er[3], s0.w, a);
      a = fmaf(Er[4], s1.x, a);  a = fmaf(Er[5], s1.y, a);
      a = fmaf(Er[6], s1.z, a);  a = fmaf(Er[7], s1.w, a);
      a = fmaf(Er[8], s2.x, a);  a = fmaf(Er[9], s2.y, a);
      a = fmaf(Er[10], s2.z, a); a = fmaf(Er[11], s2.w, a);
      a = fmaf(Er[12], s3.x, a); a = fmaf(Er[13], s3.y, a);
      a = fmaf(Er[14], s3.z, a); a = fmaf(Er[15], s3.w, a);
      a = fmaf(Ur[0], x0.x, a);  a = fmaf(Ur[1], x0.y, a);
      a = fmaf(Ur[2], x0.z, a);  a = fmaf(Ur[3], x0.w, a);
      a = fmaf(Ur[4], x1.x, a);  a = fmaf(Ur[5], x1.y, a);
      a = fmaf(Ur[6], x1.z, a);  a = fmaf(Ur[7], x1.w, a);
      a = fmaf(Ur[8], x2.x, a);  a = fmaf(Ur[9], x2.y, a);
      a = fmaf(Ur[10], x2.z, a); a = fmaf(Ur[11], x2.w, a);
      a = fmaf(Ur[12], x3.x, a); a = fmaf(Ur[13], x3.y, a);
      a = fmaf(Ur[14], x3.z, a); a = fmaf(Ur[15], x3.w, a);
      acc[b] = a;
    }
#pragma unroll
    for (int b = 0; b < BPB; ++b) pr[q][b][n] = acc[b];
    __syncthreads();                            // B2: pr ready
    if (rb < BPB)
      Ss[rb][n] = pr[0][rb][n] + pr[1][rb][n] + pr[2][rb][n] + pr[3][rb][n];
    __syncthreads();                            // B3: Ss updated
  }
}

// Output as LDS-tiled GEMM, 1 column-chunk per block (grid (Dz,4), 1024
// blocks; 2 resident/CU by LDS, dispatch pipelines the rest).
__global__ __launch_bounds__(256, 2) void s4_out5(
    const float* __restrict__ xT, const float* __restrict__ S,
    const float* __restrict__ Qk, const float* __restrict__ kloc,
    const float* __restrict__ dts, float* __restrict__ yT) {
  __shared__ alignas(16) float Ms[64 * SM];   // [r][k]  k<64: W, k>=64: T
  __shared__ alignas(16) float Zs[64 * SM];   // [col][k] k<64: S, k>=64: X
  __shared__ float Qs[(KE + 1) * Nz];
  __shared__ float CT[KE + 1][66];
  __shared__ float kx[64];
  const int d = blockIdx.x;
  const int ch = blockIdx.y;                  // which 8 (b,c)-columns block
  const int tid = threadIdx.x;
  const int tc = tid & 15, tr = tid >> 4;
  const float dt = dts[d];
  if (tid < 65) {
    const float rdt = (float)tid * dt;
    float c = 1.f;
    CT[0][tid] = 1.f;
#pragma unroll
    for (int k = 1; k <= KE; ++k) { c *= rdt / (float)k; CT[k][tid] = c; }
  }
  for (int idx = tid; idx < (KE + 1) * 64; idx += 256)
    Qs[idx] = Qk[(size_t)d * ((KE + 1) * 64) + idx];
  if (tid < 64) kx[tid] = kloc[d * 64 + tid];
  __syncthreads();
#pragma unroll
  for (int i = 0; i < 16; ++i) {
    const int e = tid + 256 * i;
    const int r = e >> 6, m = e & 63;
    float w = 0.f;
#pragma unroll
    for (int k = 0; k <= KE; ++k) w = fmaf(CT[k][r + 1], Qs[k * 64 + m], w);
    Ms[r * SM + m] = w;
  }
#pragma unroll
  for (int i = 0; i < 16; ++i) {
    const int e = tid + 256 * i;
    const int r = e >> 6, j = e & 63;
    Ms[r * SM + 64 + j] = (j <= r) ? kx[r - j] : 0.f;
  }
  const float* xd = xT + (size_t)d * Bz * Lz;
  const float* Sd = S + (size_t)d * (32 * 8 * 64);
  float* yd = yT + (size_t)d * Bz * Lz;
  const int lcol = tid >> 2, seg = tid & 3;
  const int sbb = lcol & 7, sccl = lcol >> 3;
  {
    const int cc = ch * 8 + sccl;
    const float* sp = Sd + cc * 512 + sbb * 64 + seg * 16;
    const float* xp = xd + (size_t)sbb * Lz + cc * 64 + seg * 16;
    float* zrow = Zs + lcol * SM;
#pragma unroll
    for (int i = 0; i < 4; ++i) {
      *(float4*)(zrow + seg * 16 + i * 4) = *(const float4*)(sp + i * 4);
      *(float4*)(zrow + 64 + seg * 16 + i * 4) = *(const float4*)(xp + i * 4);
    }
  }
  __syncthreads();
  float acc[16];
#pragma unroll
  for (int i = 0; i < 16; ++i) acc[i] = 0.f;
#pragma unroll 4
  for (int k = 0; k < 128; k += 4) {
    float4 mv[4], zv[4];
#pragma unroll
    for (int i = 0; i < 4; ++i)
      mv[i] = *(const float4*)&Ms[(tr * 4 + i) * SM + k];
#pragma unroll
    for (int jj = 0; jj < 4; ++jj)
      zv[jj] = *(const float4*)&Zs[(tc + 16 * jj) * SM + k];
#pragma unroll
    for (int i = 0; i < 4; ++i)
#pragma unroll
      for (int jj = 0; jj < 4; ++jj) {
        acc[i * 4 + jj] = fmaf(mv[i].x, zv[jj].x, acc[i * 4 + jj]);
        acc[i * 4 + jj] = fmaf(mv[i].y, zv[jj].y, acc[i * 4 + jj]);
        acc[i * 4 + jj] = fmaf(mv[i].z, zv[jj].z, acc[i * 4 + jj]);
        acc[i * 4 + jj] = fmaf(mv[i].w, zv[jj].w, acc[i * 4 + jj]);
      }
  }
  __syncthreads();               // done reading Zs; reuse as y staging
#pragma unroll
  for (int i = 0; i < 4; ++i)
#pragma unroll
    for (int jj = 0; jj < 4; ++jj)
      Zs[(tc + 16 * jj) * SM + tr * 4 + i] = acc[i * 4 + jj];
  __syncthreads();
  {
    const int cc = ch * 8 + sccl;
    float* yp = yd + (size_t)sbb * Lz + cc * 64 + seg * 16;
    const float* zrow = Zs + lcol * SM;
#pragma unroll
    for (int i = 0; i < 4; ++i)
      *(float4*)(yp + i * 4) = *(const float4*)(zrow + seg * 16 + i * 4);
  }
}

// Final GEMM v3: 128x64 tile, 8x4 microtile, grid 512 = 2 blocks/CU.
__global__ __launch_bounds__(256, 2) void s4_gemm3(
    const float* __restrict__ yT, const float* __restrict__ xT,
    const float* __restrict__ skip_D, const float* __restrict__ Wo,
    const float* __restrict__ bo, float* __restrict__ out) {
  __shared__ alignas(16) float Ys2[16 * SG];   // [dk][row 0..127]
  __shared__ float Ws2[16 * SW];               // [dk][col 0..63]
  const int tid = threadIdx.x;
  const int r0 = blockIdx.x * 128;
  const int c0 = blockIdx.y * 64;
  const int brow = r0 >> 11;
  const int t0 = r0 & 2047;
  const int tr = tid >> 4, tc = tid & 15;
  const int ytt = tid & 127, ydh = tid >> 7;
  const int wr = tid >> 2, wq = tid & 3;
  float acc[32];
#pragma unroll
  for (int i = 0; i < 32; ++i) acc[i] = 0.f;
#pragma unroll 1
  for (int kc = 0; kc < 16; ++kc) {
    const int dc0 = kc * 16;
#pragma unroll
    for (int p = 0; p < 8; ++p) {
      const int dk = p * 2 + ydh;
      const int dd = dc0 + dk;
      const size_t off = ((size_t)dd * Bz + brow) * Lz + t0 + ytt;
      Ys2[dk * SG + ytt] = yT[off] + xT[off] * skip_D[dd];
    }
    {
      const float4 w4 = *(const float4*)(Wo + (size_t)(c0 + wr) * Dz + dc0 + wq * 4);
      Ws2[(wq * 4 + 0) * SW + wr] = w4.x;
      Ws2[(wq * 4 + 1) * SW + wr] = w4.y;
      Ws2[(wq * 4 + 2) * SW + wr] = w4.z;
      Ws2[(wq * 4 + 3) * SW + wr] = w4.w;
    }
    __syncthreads();
#pragma unroll
    for (int dk = 0; dk < 16; ++dk) {
      const float4 a0 = *(const float4*)&Ys2[dk * SG + tr * 8];
      const float4 a1 = *(const float4*)&Ys2[dk * SG + tr * 8 + 4];
      float bv[4];
#pragma unroll
      for (int jj = 0; jj < 4; ++jj) bv[jj] = Ws2[dk * SW + tc + 16 * jj];
#pragma unroll
      for (int jj = 0; jj < 4; ++jj) {
        acc[0 * 4 + jj] = fmaf(a0.x, bv[jj], acc[0 * 4 + jj]);
        acc[1 * 4 + jj] = fmaf(a0.y, bv[jj], acc[1 * 4 + jj]);
        acc[2 * 4 + jj] = fmaf(a0.z, bv[jj], acc[2 * 4 + jj]);
        acc[3 * 4 + jj] = fmaf(a0.w, bv[jj], acc[3 * 4 + jj]);
        acc[4 * 4 + jj] = fmaf(a1.x, bv[jj], acc[4 * 4 + jj]);
        acc[5 * 4 + jj] = fmaf(a1.y, bv[jj], acc[5 * 4 + jj]);
        acc[6 * 4 + jj] = fmaf(a1.z, bv[jj], acc[6 * 4 + jj]);
        acc[7 * 4 + jj] = fmaf(a1.w, bv[jj], acc[7 * 4 + jj]);
      }
    }
    __syncthreads();
  }
  float bb[4];
#pragma unroll
  for (int jj = 0; jj < 4; ++jj) bb[jj] = bo[c0 + tc + 16 * jj];
#pragma unroll
  for (int i = 0; i < 8; ++i) {
    float* op = out + (size_t)(r0 + tr * 8 + i) * Dz + c0 + tc;
#pragma unroll
    for (int jj = 0; jj < 4; ++jj)
      op[16 * jj] = acc[i * 4 + jj] + bb[jj];
  }
}

extern "C" void kernel_launch(void* const* d_in, const int* in_sizes, int n_in,
                              void* d_out, int out_size, void* d_ws, size_t ws_size,
                              hipStream_t stream) {
  const float* x         = (const float*)d_in[0];
  const float* log_A     = (const float*)d_in[1];
  const float* Bp        = (const float*)d_in[2];
  const float* Cp        = (const float*)d_in[3];
  const float* log_delta = (const float*)d_in[4];
  const float* skip_D    = (const float*)d_in[5];
  const float* W_out     = (const float*)d_in[6];
  const float* b_out     = (const float*)d_in[7];
  float* out = (float*)d_out;

  float* xT   = (float*)d_ws;
  float* yT   = xT + (size_t)Dz * Bz * Lz;
  float* S    = yT + (size_t)Dz * Bz * Lz;
  float* Apow = S + (size_t)Dz * (32 * 8 * 64);
  float* Gk   = Apow + (size_t)8 * 4096;
  float* Qk   = Gk + (size_t)Dz * (KE + 1) * 64;
  float* kloc = Qk + (size_t)Dz * (KE + 1) * 64;
  float* dts  = kloc + (size_t)Dz * 64;

  hipLaunchKernelGGL(s4_xt, dim3(Lz / 64, Dz / 64, Bz), dim3(256), 0, stream,
                     x, xT, log_A, Apow);
  hipLaunchKernelGGL(s4_buildpow, dim3(Dz + 3), dim3(256), 0, stream,
                     Apow, Bp, Cp, log_delta, Gk, Qk, kloc, dts);
  hipLaunchKernelGGL(s4_scan4, dim3(Dz, BSP), dim3(256), 0, stream,
                     xT, Apow, Gk, dts, S);
  hipLaunchKernelGGL(s4_out5, dim3(Dz, 4), dim3(256), 0, stream,
                     xT, S, Qk, kloc, dts, yT);
  hipLaunchKernelGGL(s4_gemm3, dim3((Bz * Lz) / 128, Dz / 64), dim3(256), 0, stream,
                     yT, xT, skip_D, W_out, b_out, out);
}

// Round 14
// 168.230 us; speedup vs baseline: 1.5878x; 1.1452x over previous
//
#include <hip/hip_runtime.h>

#define Bz 8
#define Lz 2048
#define Dz 256
#define Nz 64
#define SP 68   // b128-aligned LDS stride (power matmuls)
#define SA 65   // scalar-access LDS stride (conflict-free rows+cols)
#define SM 132  // out6 LDS stride
#define SAK 40  // gemm4 bf16 LDS stride (16B-aligned rows)
#define KE 4    // Taylor order: ||64*dt*A|| <= ~0.15 -> rel err ~6e-7
#define KP 7    // p-chain depth = KE + 3 (dB phi1 terms)
#define BSP 4   // scan: blocks per channel (batch split)
#define BPB (Bz / BSP)   // 2 batches per block

typedef __attribute__((ext_vector_type(8))) short bf16x8;
typedef __attribute__((ext_vector_type(4))) float f32x4;

__device__ __forceinline__ float softplusf(float x) {
  return (x > 20.f) ? x : log1pf(expf(x));
}

__device__ __forceinline__ unsigned short f2bf(float f) {  // RNE fp32->bf16
  unsigned int u = __float_as_uint(f);
  u += 0x7fffu + ((u >> 16) & 1u);
  return (unsigned short)(u >> 16);
}

// acc = row n of (LA * LB), cols q*16..q*16+15 (SP strides). No barriers.
__device__ __forceinline__ void pmm_acc(const float* __restrict__ LA,
                                        const float* __restrict__ LB,
                                        float* acc, int n, int q) {
  float arow[64];
#pragma unroll
  for (int mm = 0; mm < 16; ++mm) {
    const float4 a4 = *(const float4*)(LA + n * SP + mm * 4);
    arow[4 * mm + 0] = a4.x; arow[4 * mm + 1] = a4.y;
    arow[4 * mm + 2] = a4.z; arow[4 * mm + 3] = a4.w;
  }
#pragma unroll
  for (int i = 0; i < 16; ++i) acc[i] = 0.f;
#pragma unroll 8
  for (int m = 0; m < 64; ++m) {
    const float4 b0 = *(const float4*)(LB + m * SP + q * 16 + 0);
    const float4 b1 = *(const float4*)(LB + m * SP + q * 16 + 4);
    const float4 b2 = *(const float4*)(LB + m * SP + q * 16 + 8);
    const float4 b3 = *(const float4*)(LB + m * SP + q * 16 + 12);
    const float a = arow[m];
    acc[0]  = fmaf(a, b0.x, acc[0]);  acc[1]  = fmaf(a, b0.y, acc[1]);
    acc[2]  = fmaf(a, b0.z, acc[2]);  acc[3]  = fmaf(a, b0.w, acc[3]);
    acc[4]  = fmaf(a, b1.x, acc[4]);  acc[5]  = fmaf(a, b1.y, acc[5]);
    acc[6]  = fmaf(a, b1.z, acc[6]);  acc[7]  = fmaf(a, b1.w, acc[7]);
    acc[8]  = fmaf(a, b2.x, acc[8]);  acc[9]  = fmaf(a, b2.y, acc[9]);
    acc[10] = fmaf(a, b2.z, acc[10]); acc[11] = fmaf(a, b2.w, acc[11]);
    acc[12] = fmaf(a, b3.x, acc[12]); acc[13] = fmaf(a, b3.y, acc[13]);
    acc[14] = fmaf(a, b3.z, acc[14]); acc[15] = fmaf(a, b3.w, acc[15]);
  }
}

// ---- Transpose x[b][t][d] -> xT[d][b][t] (float4 both sides);
//      folds powinit (Apow[0] = softplus(log_A)). ----
__global__ __launch_bounds__(256) void s4_xt(const float* __restrict__ x,
                                             float* __restrict__ xT,
                                             const float* __restrict__ log_A,
                                             float* __restrict__ Apow) {
  if (blockIdx.x == 0 && blockIdx.y == 0) {
    const int i = blockIdx.z * 512 + threadIdx.x;
    Apow[i] = softplusf(log_A[i]);
    Apow[i + 256] = softplusf(log_A[i + 256]);
  }
  __shared__ float tile[64][69];   // stride 69: column reads are 2-way (free)
  const int t0 = blockIdx.x * 64, d0 = blockIdx.y * 64, b = blockIdx.z;
  const int rr = threadIdx.x >> 4;          // 0..15
  const int c4 = (threadIdx.x & 15) * 4;    // 0..60
#pragma unroll
  for (int p = 0; p < 4; ++p) {
    const int row = p * 16 + rr;            // t within tile
    const float4 v = *(const float4*)(x + ((size_t)b * Lz + t0 + row) * Dz + d0 + c4);
    tile[row][c4 + 0] = v.x; tile[row][c4 + 1] = v.y;
    tile[row][c4 + 2] = v.z; tile[row][c4 + 3] = v.w;
  }
  __syncthreads();
#pragma unroll
  for (int p = 0; p < 4; ++p) {
    const int dd = p * 16 + rr;             // d within tile
    float4 o;
    o.x = tile[c4 + 0][dd]; o.y = tile[c4 + 1][dd];
    o.z = tile[c4 + 2][dd]; o.w = tile[c4 + 3][dd];
    *(float4*)(xT + ((size_t)(d0 + dd) * Bz + b) * Lz + t0 + c4) = o;
  }
}

// ---- fused build + power-basis: blocks 0..255 per-d chains; blocks
//      256..258 compute A2 / A3 / A4 ----
__global__ __launch_bounds__(256, 1) void s4_buildpow(
    float* __restrict__ Apow, const float* __restrict__ Bp,
    const float* __restrict__ Cp, const float* __restrict__ log_delta,
    float* __restrict__ Gk, float* __restrict__ Qk,
    float* __restrict__ kloc, float* __restrict__ dts) {
  __shared__ float As[Nz * SA];
  __shared__ float Pst[KP + 1][Nz];
  __shared__ float Qst[KE + 1][Nz];
  __shared__ float Pv[Nz], Qv[Nz], dBs[Nz];
  __shared__ float prA[4][Nz + 8], prB[4][Nz + 8];
  __shared__ float zp[KE + 1][17], zs[KE + 1];
  __shared__ alignas(16) float PA[Nz * SP];
  __shared__ alignas(16) float PB[Nz * SP];
  const int tid = threadIdx.x;
  const int d = blockIdx.x;
  const int n = tid & 63, qq = tid >> 6;

  if (d >= Dz) {
    const int role = d - Dz;   // 0 -> A2, 1 -> A3 = A*A2, 2 -> A4 = A2*A2
#pragma unroll
    for (int i = 0; i < 4; ++i) {
      const int e = (tid + 256 * i) * 4;
      const int r = e >> 6, c = e & 63;
      const float4 v = *(const float4*)(Apow + e);
      *(float4*)&PA[r * SP + c] = v;
      *(float4*)&PB[r * SP + c] = v;
    }
    __syncthreads();
    float acc[16];
    pmm_acc(PA, PB, acc, n, qq);
    if (role == 0) {
      float* O = Apow + (size_t)1 * 4096;
#pragma unroll
      for (int v = 0; v < 4; ++v) {
        float4 o;
        o.x = acc[4 * v]; o.y = acc[4 * v + 1];
        o.z = acc[4 * v + 2]; o.w = acc[4 * v + 3];
        *(float4*)(O + n * 64 + qq * 16 + 4 * v) = o;
      }
      return;
    }
    __syncthreads();
#pragma unroll
    for (int i = 0; i < 16; ++i) {
      PB[n * SP + qq * 16 + i] = acc[i];
      if (role == 2) PA[n * SP + qq * 16 + i] = acc[i];
    }
    __syncthreads();
    pmm_acc(PA, PB, acc, n, qq);
    float* O = Apow + (size_t)(role + 1) * 4096;
#pragma unroll
    for (int v = 0; v < 4; ++v) {
      float4 o;
      o.x = acc[4 * v]; o.y = acc[4 * v + 1];
      o.z = acc[4 * v + 2]; o.w = acc[4 * v + 3];
      *(float4*)(O + n * 64 + qq * 16 + 4 * v) = o;
    }
    return;
  }

  const float dt = softplusf(log_delta[d]) + 1e-6f;
#pragma unroll
  for (int i = 0; i < 4; ++i) {
    const int e = (tid + 256 * i) * 4;
    const int r = e >> 6, c = e & 63;
    const float4 v = *(const float4*)(Apow + e);
    As[r * SA + c] = v.x; As[r * SA + c + 1] = v.y;
    As[r * SA + c + 2] = v.z; As[r * SA + c + 3] = v.w;
  }
  if (tid < 64) {
    const float bv = Bp[d * Nz + tid], cv = Cp[d * Nz + tid];
    Pv[tid] = bv; Pst[0][tid] = bv;
    Qv[tid] = cv; Qst[0][tid] = cv;
  }
  __syncthreads();
#pragma unroll 1
  for (int k = 1; k <= KP; ++k) {
    float pp = 0.f, pq = 0.f;
#pragma unroll
    for (int mm = 0; mm < 16; ++mm) {
      const int m = qq * 16 + mm;
      pp += As[n * SA + m] * Pv[m];   // (A p)[n]
      pq += As[m * SA + n] * Qv[m];   // (A^T q)[n]
    }
    prA[qq][n] = pp; prB[qq][n] = pq;
    __syncthreads();
    if (tid < 64) {
      const float np = prA[0][tid] + prA[1][tid] + prA[2][tid] + prA[3][tid];
      Pv[tid] = np; Pst[k][tid] = np;
      if (k <= KE) {
        const float nq = prB[0][tid] + prB[1][tid] + prB[2][tid] + prB[3][tid];
        Qv[tid] = nq; Qst[k][tid] = nq;
      }
    }
    __syncthreads();
  }
  const float dtc0 = dt;
  const float dtc1 = dt * dt * 0.5f;
  const float dtc2 = dtc1 * dt * (1.f / 3.f);
  const float dtc3 = dtc2 * dt * 0.25f;
  if (tid < 64) {
    dBs[tid] = dtc0 * Pst[0][tid] + dtc1 * Pst[1][tid] +
               dtc2 * Pst[2][tid] + dtc3 * Pst[3][tid];
#pragma unroll
    for (int k = 0; k <= KE; ++k) {
      Gk[(size_t)d * ((KE + 1) * 64) + k * 64 + tid] =
          dtc0 * Pst[k][tid] + dtc1 * Pst[k + 1][tid] +
          dtc2 * Pst[k + 2][tid] + dtc3 * Pst[k + 3][tid];
      Qk[(size_t)d * ((KE + 1) * 64) + k * 64 + tid] = Qst[k][tid];
    }
  }
  __syncthreads();
  if (tid < (KE + 1) * 16) {
    const int k = tid >> 4, seg = tid & 15;
    float s = 0.f;
#pragma unroll
    for (int i = 0; i < 4; ++i) s += Qst[k][seg * 4 + i] * dBs[seg * 4 + i];
    zp[k][seg] = s;
  }
  __syncthreads();
  if (tid <= KE) {
    float s = 0.f;
#pragma unroll
    for (int seg = 0; seg < 16; ++seg) s += zp[tid][seg];
    zs[tid] = s;
  }
  __syncthreads();
  if (tid < 64) {
    const float rdt = (float)tid * dt;
    float c = 1.f, acc = zs[0];
#pragma unroll
    for (int k = 1; k <= KE; ++k) { c *= rdt / (float)k; acc += c * zs[k]; }
    kloc[d * 64 + tid] = acc;
  }
  if (tid == 0) dts[d] = dt;
}

// Chunked state scan v4. Grid (Dz, BSP=4): 1024 blocks = 4/CU.
__global__ __launch_bounds__(256) void s4_scan4(
    const float* __restrict__ xT, const float* __restrict__ Apow,
    const float* __restrict__ Gk, const float* __restrict__ dts,
    float* __restrict__ S) {
  __shared__ float Es[Nz * SA];
  __shared__ float Gs[(KE + 1) * Nz];
  __shared__ float CTs[KE + 1][66];
  __shared__ alignas(16) float Xs[BPB][64];
  __shared__ alignas(16) float Ss[BPB][64];
  __shared__ float pr[4][BPB][64];
  const int d = blockIdx.x;
  const int z = blockIdx.y;
  const int tid = threadIdx.x, n = tid & 63, q = tid >> 6;
  const int rb = tid >> 6;               // staging/reduce ownership (rb < BPB)
  const float dt = dts[d];
  if (tid < 65) {
    const float rdt = (float)tid * dt;
    float c = 1.f;
    CTs[0][tid] = 1.f;
#pragma unroll
    for (int k = 1; k <= KE; ++k) { c *= rdt / (float)k; CTs[k][tid] = c; }
  }
  for (int idx = tid; idx < (KE + 1) * 64; idx += 256)
    Gs[idx] = Gk[(size_t)d * ((KE + 1) * 64) + idx];
  {
    float ea[16];
#pragma unroll
    for (int i = 0; i < 16; ++i) ea[i] = 0.f;
    const float dt64 = 64.f * dt;
    float ce = 1.f;
#pragma unroll 1
    for (int k = 1; k <= KE; ++k) {
      ce *= dt64 / (float)k;
      const float* Ak = Apow + (size_t)(k - 1) * 4096;
#pragma unroll
      for (int i = 0; i < 16; ++i)
        ea[i] = fmaf(ce, Ak[tid + 256 * i], ea[i]);
    }
#pragma unroll
    for (int i = 0; i < 16; ++i) {
      const int e = tid + 256 * i;
      const int r = e >> 6, c = e & 63;
      Es[r * SA + c] = ea[i] + ((r == c) ? 1.f : 0.f);
    }
  }
  __syncthreads();
  float Er[16], Ur[16];
#pragma unroll
  for (int i = 0; i < 16; ++i) Er[i] = Es[n * SA + q * 16 + i];
#pragma unroll
  for (int i = 0; i < 16; ++i) {
    const int j = q * 16 + i;
    float u = 0.f;
#pragma unroll
    for (int k = 0; k <= KE; ++k) u = fmaf(CTs[k][63 - j], Gs[k * 64 + n], u);
    Ur[i] = u;                    // = Uf[n][j] = (E^{63-j} dB)[n]
  }
  if (rb < BPB) Ss[rb][n] = 0.f;
  const float* xd = xT + ((size_t)d * Bz + z * BPB) * Lz;
  float* Sd = S + (size_t)d * (32 * 8 * 64) + (size_t)(z * BPB) * 64;
#pragma unroll 1
  for (int c = 0; c < 32; ++c) {
    if (rb < BPB) {
      Xs[rb][n] = xd[(size_t)rb * Lz + c * 64 + n];
      Sd[c * 512 + rb * 64 + n] = Ss[rb][n];   // state entering chunk c
    }
    __syncthreads();                            // B1: Xs/Ss ready
    float acc[BPB];
#pragma unroll
    for (int b = 0; b < BPB; ++b) {
      const float4 s0 = *(const float4*)&Ss[b][q * 16 + 0];
      const float4 s1 = *(const float4*)&Ss[b][q * 16 + 4];
      const float4 s2 = *(const float4*)&Ss[b][q * 16 + 8];
      const float4 s3 = *(const float4*)&Ss[b][q * 16 + 12];
      const float4 x0 = *(const float4*)&Xs[b][q * 16 + 0];
      const float4 x1 = *(const float4*)&Xs[b][q * 16 + 4];
      const float4 x2 = *(const float4*)&Xs[b][q * 16 + 8];
      const float4 x3 = *(const float4*)&Xs[b][q * 16 + 12];
      float a = 0.f;
      a = fmaf(Er[0], s0.x, a);  a = fmaf(Er[1], s0.y, a);
      a = fmaf(Er[2], s0.z, a);  a = fmaf(Er[3], s0.w, a);
      a = fmaf(Er[4], s1.x, a);  a = fmaf(Er[5], s1.y, a);
      a = fmaf(Er[6], s1.z, a);  a = fmaf(Er[7], s1.w, a);
      a = fmaf(Er[8], s2.x, a);  a = fmaf(Er[9], s2.y, a);
      a = fmaf(Er[10], s2.z, a); a = fmaf(Er[11], s2.w, a);
      a = fmaf(Er[12], s3.x, a); a = fmaf(Er[13], s3.y, a);
      a = fmaf(Er[14], s3.z, a); a = fmaf(Er[15], s3.w, a);
      a = fmaf(Ur[0], x0.x, a);  a = fmaf(Ur[1], x0.y, a);
      a = fmaf(Ur[2], x0.z, a);  a = fmaf(Ur[3], x0.w, a);
      a = fmaf(Ur[4], x1.x, a);  a = fmaf(Ur[5], x1.y, a);
      a = fmaf(Ur[6], x1.z, a);  a = fmaf(Ur[7], x1.w, a);
      a = fmaf(Ur[8], x2.x, a);  a = fmaf(Ur[9], x2.y, a);
      a = fmaf(Ur[10], x2.z, a); a = fmaf(Ur[11], x2.w, a);
      a = fmaf(Ur[12], x3.x, a); a = fmaf(Ur[13], x3.y, a);
      a = fmaf(Ur[14], x3.z, a); a = fmaf(Ur[15], x3.w, a);
      acc[b] = a;
    }
#pragma unroll
    for (int b = 0; b < BPB; ++b) pr[q][b][n] = acc[b];
    __syncthreads();                            // B2: pr ready
    if (rb < BPB)
      Ss[rb][n] = pr[0][rb][n] + pr[1][rb][n] + pr[2][rb][n] + pr[3][rb][n];
    __syncthreads();                            // B3: Ss updated
  }
}

// Output GEMM per d (1 column-chunk per block, grid (Dz,4)); folds the
// skip term (x is already staged for the Toeplitz part) and emits
// yb[d][b][t] in BF16 for the MFMA final GEMM.
__global__ __launch_bounds__(256, 2) void s4_out6(
    const float* __restrict__ xT, const float* __restrict__ S,
    const float* __restrict__ Qk, const float* __restrict__ kloc,
    const float* __restrict__ dts, const float* __restrict__ skip_D,
    unsigned short* __restrict__ yb) {
  __shared__ alignas(16) float Ms[64 * SM];   // [r][k]  k<64: W, k>=64: T
  __shared__ alignas(16) float Zs[64 * SM];   // [col][k] k<64: S, k>=64: X
  __shared__ float Qs[(KE + 1) * Nz];
  __shared__ float CT[KE + 1][66];
  __shared__ float kx[64];
  const int d = blockIdx.x;
  const int ch = blockIdx.y;
  const int tid = threadIdx.x;
  const int tc = tid & 15, tr = tid >> 4;
  const float dt = dts[d];
  const float sd = skip_D[d];
  if (tid < 65) {
    const float rdt = (float)tid * dt;
    float c = 1.f;
    CT[0][tid] = 1.f;
#pragma unroll
    for (int k = 1; k <= KE; ++k) { c *= rdt / (float)k; CT[k][tid] = c; }
  }
  for (int idx = tid; idx < (KE + 1) * 64; idx += 256)
    Qs[idx] = Qk[(size_t)d * ((KE + 1) * 64) + idx];
  if (tid < 64) kx[tid] = kloc[d * 64 + tid];
  __syncthreads();
#pragma unroll
  for (int i = 0; i < 16; ++i) {
    const int e = tid + 256 * i;
    const int r = e >> 6, m = e & 63;
    float w = 0.f;
#pragma unroll
    for (int k = 0; k <= KE; ++k) w = fmaf(CT[k][r + 1], Qs[k * 64 + m], w);
    Ms[r * SM + m] = w;
  }
#pragma unroll
  for (int i = 0; i < 16; ++i) {
    const int e = tid + 256 * i;
    const int r = e >> 6, j = e & 63;
    Ms[r * SM + 64 + j] = (j <= r) ? kx[r - j] : 0.f;
  }
  const float* xd = xT + (size_t)d * Bz * Lz;
  const float* Sd = S + (size_t)d * (32 * 8 * 64);
  const int lcol = tid >> 2, seg = tid & 3;
  const int sbb = lcol & 7, sccl = lcol >> 3;
  {
    const int cc = ch * 8 + sccl;
    const float* sp = Sd + cc * 512 + sbb * 64 + seg * 16;
    const float* xp = xd + (size_t)sbb * Lz + cc * 64 + seg * 16;
    float* zrow = Zs + lcol * SM;
#pragma unroll
    for (int i = 0; i < 4; ++i) {
      *(float4*)(zrow + seg * 16 + i * 4) = *(const float4*)(sp + i * 4);
      *(float4*)(zrow + 64 + seg * 16 + i * 4) = *(const float4*)(xp + i * 4);
    }
  }
  __syncthreads();
  float acc[16];
#pragma unroll
  for (int i = 0; i < 16; ++i) acc[i] = 0.f;
#pragma unroll 4
  for (int k = 0; k < 128; k += 4) {
    float4 mv[4], zv[4];
#pragma unroll
    for (int i = 0; i < 4; ++i)
      mv[i] = *(const float4*)&Ms[(tr * 4 + i) * SM + k];
#pragma unroll
    for (int jj = 0; jj < 4; ++jj)
      zv[jj] = *(const float4*)&Zs[(tc + 16 * jj) * SM + k];
#pragma unroll
    for (int i = 0; i < 4; ++i)
#pragma unroll
      for (int jj = 0; jj < 4; ++jj) {
        acc[i * 4 + jj] = fmaf(mv[i].x, zv[jj].x, acc[i * 4 + jj]);
        acc[i * 4 + jj] = fmaf(mv[i].y, zv[jj].y, acc[i * 4 + jj]);
        acc[i * 4 + jj] = fmaf(mv[i].z, zv[jj].z, acc[i * 4 + jj]);
        acc[i * 4 + jj] = fmaf(mv[i].w, zv[jj].w, acc[i * 4 + jj]);
      }
  }
  // skip fold: y += skip_D[d] * x (x still staged at Zs[col][64 + r])
#pragma unroll
  for (int i = 0; i < 4; ++i)
#pragma unroll
    for (int jj = 0; jj < 4; ++jj)
      acc[i * 4 + jj] =
          fmaf(sd, Zs[(tc + 16 * jj) * SM + 64 + tr * 4 + i], acc[i * 4 + jj]);
  __syncthreads();               // done reading Zs; reuse as y staging
#pragma unroll
  for (int i = 0; i < 4; ++i)
#pragma unroll
    for (int jj = 0; jj < 4; ++jj)
      Zs[(tc + 16 * jj) * SM + tr * 4 + i] = acc[i * 4 + jj];
  __syncthreads();
  {
    const int cc = ch * 8 + sccl;
    unsigned short* yp =
        yb + ((size_t)d * Bz + sbb) * Lz + cc * 64 + seg * 16;
    const float* zrow = Zs + lcol * SM;
#pragma unroll
    for (int i = 0; i < 4; ++i) {
      ushort4 o;
      o.x = f2bf(zrow[seg * 16 + i * 4 + 0]);
      o.y = f2bf(zrow[seg * 16 + i * 4 + 1]);
      o.z = f2bf(zrow[seg * 16 + i * 4 + 2]);
      o.w = f2bf(zrow[seg * 16 + i * 4 + 3]);
      *(ushort4*)(yp + i * 4) = o;
    }
  }
}

// Final GEMM v4 (MFMA bf16): out[row][c] = sum_d yb[d][row] * Wo[c][d] + bo[c]
// Block tile 128x64, 4 waves x (2 m-tiles x 4 n-tiles) of 16x16x32 MFMAs,
// 8 K-steps of 32. Verified layouts: A[m=lane&15][k=quad*8+j],
// B[k=quad*8+j][n=lane&15], D col=lane&15 row=quad*4+reg (m89/m120).
__global__ __launch_bounds__(256, 2) void s4_gemm4(
    const unsigned short* __restrict__ yb, const float* __restrict__ Wo,
    const float* __restrict__ bo, float* __restrict__ out) {
  __shared__ alignas(16) unsigned short LA[128 * SAK];  // [row(t)][k'(d)]
  __shared__ alignas(16) unsigned short LB[64 * SAK];   // [c][k'(d)]
  const int tid = threadIdx.x;
  const int wave = tid >> 6, lane = tid & 63;
  const int quad = lane >> 4, lq = lane & 15;
  const int r0 = blockIdx.x * 128;
  const int c0 = blockIdx.y * 64;
  const int brow = r0 >> 11, t0 = r0 & 2047;
  const int ad = tid & 31;          // A staging: d-offset 0..31
  const int atp = tid >> 5;         // A staging: t-pair 0..7
  const int bc = tid >> 2;          // B staging: c-offset 0..63
  const int bko = tid & 3;          // B staging: k-octet 0..3
  f32x4 acc[2][4];
#pragma unroll
  for (int mi = 0; mi < 2; ++mi)
#pragma unroll
    for (int ni = 0; ni < 4; ++ni)
#pragma unroll
      for (int i = 0; i < 4; ++i) acc[mi][ni][i] = 0.f;
#pragma unroll 1
  for (int ks = 0; ks < 8; ++ks) {
    const int k0 = ks * 32;
    // stage A: yb[(k0+ad)][brow][t0 + atp*16 .. +15] -> LA[t][ad] (transpose)
    {
      const unsigned short* src =
          yb + ((size_t)(k0 + ad) * Bz + brow) * Lz + t0 + atp * 16;
#pragma unroll
      for (int h = 0; h < 2; ++h) {
        const bf16x8 v = *(const bf16x8*)(src + h * 8);
#pragma unroll
        for (int j = 0; j < 8; ++j)
          LA[(atp * 16 + h * 8 + j) * SAK + ad] = (unsigned short)v[j];
      }
    }
    // stage B: Wo[c0+bc][k0 + bko*8 .. +7] fp32 -> bf16 -> LB[bc][bko*8..]
    {
      const float* wsrc = Wo + (size_t)(c0 + bc) * Dz + k0 + bko * 8;
      const float4 w0 = *(const float4*)(wsrc);
      const float4 w1 = *(const float4*)(wsrc + 4);
      bf16x8 wv;
      wv[0] = (short)f2bf(w0.x); wv[1] = (short)f2bf(w0.y);
      wv[2] = (short)f2bf(w0.z); wv[3] = (short)f2bf(w0.w);
      wv[4] = (short)f2bf(w1.x); wv[5] = (short)f2bf(w1.y);
      wv[6] = (short)f2bf(w1.z); wv[7] = (short)f2bf(w1.w);
      *(bf16x8*)&LB[bc * SAK + bko * 8] = wv;
    }
    __syncthreads();
    bf16x8 af[2], bfr[4];
#pragma unroll
    for (int mi = 0; mi < 2; ++mi)
      af[mi] = *(const bf16x8*)&LA[(wave * 32 + mi * 16 + lq) * SAK + quad * 8];
#pragma unroll
    for (int ni = 0; ni < 4; ++ni)
      bfr[ni] = *(const bf16x8*)&LB[(ni * 16 + lq) * SAK + quad * 8];
#pragma unroll
    for (int mi = 0; mi < 2; ++mi)
#pragma unroll
      for (int ni = 0; ni < 4; ++ni)
        acc[mi][ni] = __builtin_amdgcn_mfma_f32_16x16x32_bf16(
            af[mi], bfr[ni], acc[mi][ni], 0, 0, 0);
    __syncthreads();
  }
  float bb[4];
#pragma unroll
  for (int ni = 0; ni < 4; ++ni) bb[ni] = bo[c0 + ni * 16 + lq];
#pragma unroll
  for (int mi = 0; mi < 2; ++mi)
#pragma unroll
    for (int i = 0; i < 4; ++i) {
      const int row = r0 + wave * 32 + mi * 16 + quad * 4 + i;
#pragma unroll
      for (int ni = 0; ni < 4; ++ni)
        out[(size_t)row * Dz + c0 + ni * 16 + lq] = acc[mi][ni][i] + bb[ni];
    }
}

extern "C" void kernel_launch(void* const* d_in, const int* in_sizes, int n_in,
                              void* d_out, int out_size, void* d_ws, size_t ws_size,
                              hipStream_t stream) {
  const float* x         = (const float*)d_in[0];
  const float* log_A     = (const float*)d_in[1];
  const float* Bp        = (const float*)d_in[2];
  const float* Cp        = (const float*)d_in[3];
  const float* log_delta = (const float*)d_in[4];
  const float* skip_D    = (const float*)d_in[5];
  const float* W_out     = (const float*)d_in[6];
  const float* b_out     = (const float*)d_in[7];
  float* out = (float*)d_out;

  float* xT   = (float*)d_ws;
  float* ybf  = xT + (size_t)Dz * Bz * Lz;       // bf16 yb lives in this slot
  float* S    = ybf + (size_t)Dz * Bz * Lz;
  float* Apow = S + (size_t)Dz * (32 * 8 * 64);
  float* Gk   = Apow + (size_t)8 * 4096;
  float* Qk   = Gk + (size_t)Dz * (KE + 1) * 64;
  float* kloc = Qk + (size_t)Dz * (KE + 1) * 64;
  float* dts  = kloc + (size_t)Dz * 64;
  unsigned short* yb = (unsigned short*)ybf;

  hipLaunchKernelGGL(s4_xt, dim3(Lz / 64, Dz / 64, Bz), dim3(256), 0, stream,
                     x, xT, log_A, Apow);
  hipLaunchKernelGGL(s4_buildpow, dim3(Dz + 3), dim3(256), 0, stream,
                     Apow, Bp, Cp, log_delta, Gk, Qk, kloc, dts);
  hipLaunchKernelGGL(s4_scan4, dim3(Dz, BSP), dim3(256), 0, stream,
                     xT, Apow, Gk, dts, S);
  hipLaunchKernelGGL(s4_out6, dim3(Dz, 4), dim3(256), 0, stream,
                     xT, S, Qk, kloc, dts, skip_D, yb);
  hipLaunchKernelGGL(s4_gemm4, dim3((Bz * Lz) / 128, Dz / 64), dim3(256), 0, stream,
                     yb, W_out, b_out, out);
}

// Round 15
// 154.096 us; speedup vs baseline: 1.7334x; 1.0917x over previous
//
#include <hip/hip_runtime.h>

#define Bz 8
#define Lz 2048
#define Dz 256
#define Nz 64
#define SP 68   // b128-aligned LDS stride (power matmuls)
#define SA 65   // scalar-access LDS stride (conflict-free rows+cols)
#define SAK 40  // gemm4 bf16 LDS stride (ushorts)
#define SKB 136 // out7 bf16 LDS stride (ushorts): 272B rows, 16B-aligned
#define KE 4    // Taylor order: ||64*dt*A|| <= ~0.15 -> rel err ~6e-7
#define KP 7    // p-chain depth = KE + 3 (dB phi1 terms)
#define BSP 4   // scan: blocks per channel (batch split)
#define BPB (Bz / BSP)   // 2 batches per block

typedef __attribute__((ext_vector_type(8))) short bf16x8;
typedef __attribute__((ext_vector_type(4))) float f32x4;

__device__ __forceinline__ float softplusf(float x) {
  return (x > 20.f) ? x : log1pf(expf(x));
}

__device__ __forceinline__ unsigned short f2bf(float f) {  // RNE fp32->bf16
  unsigned int u = __float_as_uint(f);
  u += 0x7fffu + ((u >> 16) & 1u);
  return (unsigned short)(u >> 16);
}

// acc = row n of (LA * LB), cols q*16..q*16+15 (SP strides). No barriers.
__device__ __forceinline__ void pmm_acc(const float* __restrict__ LA,
                                        const float* __restrict__ LB,
                                        float* acc, int n, int q) {
  float arow[64];
#pragma unroll
  for (int mm = 0; mm < 16; ++mm) {
    const float4 a4 = *(const float4*)(LA + n * SP + mm * 4);
    arow[4 * mm + 0] = a4.x; arow[4 * mm + 1] = a4.y;
    arow[4 * mm + 2] = a4.z; arow[4 * mm + 3] = a4.w;
  }
#pragma unroll
  for (int i = 0; i < 16; ++i) acc[i] = 0.f;
#pragma unroll 8
  for (int m = 0; m < 64; ++m) {
    const float4 b0 = *(const float4*)(LB + m * SP + q * 16 + 0);
    const float4 b1 = *(const float4*)(LB + m * SP + q * 16 + 4);
    const float4 b2 = *(const float4*)(LB + m * SP + q * 16 + 8);
    const float4 b3 = *(const float4*)(LB + m * SP + q * 16 + 12);
    const float a = arow[m];
    acc[0]  = fmaf(a, b0.x, acc[0]);  acc[1]  = fmaf(a, b0.y, acc[1]);
    acc[2]  = fmaf(a, b0.z, acc[2]);  acc[3]  = fmaf(a, b0.w, acc[3]);
    acc[4]  = fmaf(a, b1.x, acc[4]);  acc[5]  = fmaf(a, b1.y, acc[5]);
    acc[6]  = fmaf(a, b1.z, acc[6]);  acc[7]  = fmaf(a, b1.w, acc[7]);
    acc[8]  = fmaf(a, b2.x, acc[8]);  acc[9]  = fmaf(a, b2.y, acc[9]);
    acc[10] = fmaf(a, b2.z, acc[10]); acc[11] = fmaf(a, b2.w, acc[11]);
    acc[12] = fmaf(a, b3.x, acc[12]); acc[13] = fmaf(a, b3.y, acc[13]);
    acc[14] = fmaf(a, b3.z, acc[14]); acc[15] = fmaf(a, b3.w, acc[15]);
  }
}

// ---- Transpose x[b][t][d] -> xT[d][b][t] (float4 both sides);
//      folds powinit (Apow[0] = softplus(log_A)). ----
__global__ __launch_bounds__(256) void s4_xt(const float* __restrict__ x,
                                             float* __restrict__ xT,
                                             const float* __restrict__ log_A,
                                             float* __restrict__ Apow) {
  if (blockIdx.x == 0 && blockIdx.y == 0) {
    const int i = blockIdx.z * 512 + threadIdx.x;
    Apow[i] = softplusf(log_A[i]);
    Apow[i + 256] = softplusf(log_A[i + 256]);
  }
  __shared__ float tile[64][69];
  const int t0 = blockIdx.x * 64, d0 = blockIdx.y * 64, b = blockIdx.z;
  const int rr = threadIdx.x >> 4;
  const int c4 = (threadIdx.x & 15) * 4;
#pragma unroll
  for (int p = 0; p < 4; ++p) {
    const int row = p * 16 + rr;
    const float4 v = *(const float4*)(x + ((size_t)b * Lz + t0 + row) * Dz + d0 + c4);
    tile[row][c4 + 0] = v.x; tile[row][c4 + 1] = v.y;
    tile[row][c4 + 2] = v.z; tile[row][c4 + 3] = v.w;
  }
  __syncthreads();
#pragma unroll
  for (int p = 0; p < 4; ++p) {
    const int dd = p * 16 + rr;
    float4 o;
    o.x = tile[c4 + 0][dd]; o.y = tile[c4 + 1][dd];
    o.z = tile[c4 + 2][dd]; o.w = tile[c4 + 3][dd];
    *(float4*)(xT + ((size_t)(d0 + dd) * Bz + b) * Lz + t0 + c4) = o;
  }
}

// ---- fused build + power-basis: blocks 0..255 per-d chains; blocks
//      256..258 compute A2 / A3 / A4 ----
__global__ __launch_bounds__(256, 1) void s4_buildpow(
    float* __restrict__ Apow, const float* __restrict__ Bp,
    const float* __restrict__ Cp, const float* __restrict__ log_delta,
    float* __restrict__ Gk, float* __restrict__ Qk,
    float* __restrict__ kloc, float* __restrict__ dts) {
  __shared__ float As[Nz * SA];
  __shared__ float Pst[KP + 1][Nz];
  __shared__ float Qst[KE + 1][Nz];
  __shared__ float Pv[Nz], Qv[Nz], dBs[Nz];
  __shared__ float prA[4][Nz + 8], prB[4][Nz + 8];
  __shared__ float zp[KE + 1][17], zs[KE + 1];
  __shared__ alignas(16) float PA[Nz * SP];
  __shared__ alignas(16) float PB[Nz * SP];
  const int tid = threadIdx.x;
  const int d = blockIdx.x;
  const int n = tid & 63, qq = tid >> 6;

  if (d >= Dz) {
    const int role = d - Dz;   // 0 -> A2, 1 -> A3 = A*A2, 2 -> A4 = A2*A2
#pragma unroll
    for (int i = 0; i < 4; ++i) {
      const int e = (tid + 256 * i) * 4;
      const int r = e >> 6, c = e & 63;
      const float4 v = *(const float4*)(Apow + e);
      *(float4*)&PA[r * SP + c] = v;
      *(float4*)&PB[r * SP + c] = v;
    }
    __syncthreads();
    float acc[16];
    pmm_acc(PA, PB, acc, n, qq);
    if (role == 0) {
      float* O = Apow + (size_t)1 * 4096;
#pragma unroll
      for (int v = 0; v < 4; ++v) {
        float4 o;
        o.x = acc[4 * v]; o.y = acc[4 * v + 1];
        o.z = acc[4 * v + 2]; o.w = acc[4 * v + 3];
        *(float4*)(O + n * 64 + qq * 16 + 4 * v) = o;
      }
      return;
    }
    __syncthreads();
#pragma unroll
    for (int i = 0; i < 16; ++i) {
      PB[n * SP + qq * 16 + i] = acc[i];
      if (role == 2) PA[n * SP + qq * 16 + i] = acc[i];
    }
    __syncthreads();
    pmm_acc(PA, PB, acc, n, qq);
    float* O = Apow + (size_t)(role + 1) * 4096;
#pragma unroll
    for (int v = 0; v < 4; ++v) {
      float4 o;
      o.x = acc[4 * v]; o.y = acc[4 * v + 1];
      o.z = acc[4 * v + 2]; o.w = acc[4 * v + 3];
      *(float4*)(O + n * 64 + qq * 16 + 4 * v) = o;
    }
    return;
  }

  const float dt = softplusf(log_delta[d]) + 1e-6f;
#pragma unroll
  for (int i = 0; i < 4; ++i) {
    const int e = (tid + 256 * i) * 4;
    const int r = e >> 6, c = e & 63;
    const float4 v = *(const float4*)(Apow + e);
    As[r * SA + c] = v.x; As[r * SA + c + 1] = v.y;
    As[r * SA + c + 2] = v.z; As[r * SA + c + 3] = v.w;
  }
  if (tid < 64) {
    const float bv = Bp[d * Nz + tid], cv = Cp[d * Nz + tid];
    Pv[tid] = bv; Pst[0][tid] = bv;
    Qv[tid] = cv; Qst[0][tid] = cv;
  }
  __syncthreads();
#pragma unroll 1
  for (int k = 1; k <= KP; ++k) {
    float pp = 0.f, pq = 0.f;
#pragma unroll
    for (int mm = 0; mm < 16; ++mm) {
      const int m = qq * 16 + mm;
      pp += As[n * SA + m] * Pv[m];   // (A p)[n]
      pq += As[m * SA + n] * Qv[m];   // (A^T q)[n]
    }
    prA[qq][n] = pp; prB[qq][n] = pq;
    __syncthreads();
    if (tid < 64) {
      const float np = prA[0][tid] + prA[1][tid] + prA[2][tid] + prA[3][tid];
      Pv[tid] = np; Pst[k][tid] = np;
      if (k <= KE) {
        const float nq = prB[0][tid] + prB[1][tid] + prB[2][tid] + prB[3][tid];
        Qv[tid] = nq; Qst[k][tid] = nq;
      }
    }
    __syncthreads();
  }
  const float dtc0 = dt;
  const float dtc1 = dt * dt * 0.5f;
  const float dtc2 = dtc1 * dt * (1.f / 3.f);
  const float dtc3 = dtc2 * dt * 0.25f;
  if (tid < 64) {
    dBs[tid] = dtc0 * Pst[0][tid] + dtc1 * Pst[1][tid] +
               dtc2 * Pst[2][tid] + dtc3 * Pst[3][tid];
#pragma unroll
    for (int k = 0; k <= KE; ++k) {
      Gk[(size_t)d * ((KE + 1) * 64) + k * 64 + tid] =
          dtc0 * Pst[k][tid] + dtc1 * Pst[k + 1][tid] +
          dtc2 * Pst[k + 2][tid] + dtc3 * Pst[k + 3][tid];
      Qk[(size_t)d * ((KE + 1) * 64) + k * 64 + tid] = Qst[k][tid];
    }
  }
  __syncthreads();
  if (tid < (KE + 1) * 16) {
    const int k = tid >> 4, seg = tid & 15;
    float s = 0.f;
#pragma unroll
    for (int i = 0; i < 4; ++i) s += Qst[k][seg * 4 + i] * dBs[seg * 4 + i];
    zp[k][seg] = s;
  }
  __syncthreads();
  if (tid <= KE) {
    float s = 0.f;
#pragma unroll
    for (int seg = 0; seg < 16; ++seg) s += zp[tid][seg];
    zs[tid] = s;
  }
  __syncthreads();
  if (tid < 64) {
    const float rdt = (float)tid * dt;
    float c = 1.f, acc = zs[0];
#pragma unroll
    for (int k = 1; k <= KE; ++k) { c *= rdt / (float)k; acc += c * zs[k]; }
    kloc[d * 64 + tid] = acc;
  }
  if (tid == 0) dts[d] = dt;
}

// Chunked state scan v4. Grid (Dz, BSP=4): 1024 blocks = 4/CU.
__global__ __launch_bounds__(256) void s4_scan4(
    const float* __restrict__ xT, const float* __restrict__ Apow,
    const float* __restrict__ Gk, const float* __restrict__ dts,
    float* __restrict__ S) {
  __shared__ float Es[Nz * SA];
  __shared__ float Gs[(KE + 1) * Nz];
  __shared__ float CTs[KE + 1][66];
  __shared__ alignas(16) float Xs[BPB][64];
  __shared__ alignas(16) float Ss[BPB][64];
  __shared__ float pr[4][BPB][64];
  const int d = blockIdx.x;
  const int z = blockIdx.y;
  const int tid = threadIdx.x, n = tid & 63, q = tid >> 6;
  const int rb = tid >> 6;               // staging/reduce ownership (rb < BPB)
  const float dt = dts[d];
  if (tid < 65) {
    const float rdt = (float)tid * dt;
    float c = 1.f;
    CTs[0][tid] = 1.f;
#pragma unroll
    for (int k = 1; k <= KE; ++k) { c *= rdt / (float)k; CTs[k][tid] = c; }
  }
  for (int idx = tid; idx < (KE + 1) * 64; idx += 256)
    Gs[idx] = Gk[(size_t)d * ((KE + 1) * 64) + idx];
  {
    float ea[16];
#pragma unroll
    for (int i = 0; i < 16; ++i) ea[i] = 0.f;
    const float dt64 = 64.f * dt;
    float ce = 1.f;
#pragma unroll 1
    for (int k = 1; k <= KE; ++k) {
      ce *= dt64 / (float)k;
      const float* Ak = Apow + (size_t)(k - 1) * 4096;
#pragma unroll
      for (int i = 0; i < 16; ++i)
        ea[i] = fmaf(ce, Ak[tid + 256 * i], ea[i]);
    }
#pragma unroll
    for (int i = 0; i < 16; ++i) {
      const int e = tid + 256 * i;
      const int r = e >> 6, c = e & 63;
      Es[r * SA + c] = ea[i] + ((r == c) ? 1.f : 0.f);
    }
  }
  __syncthreads();
  float Er[16], Ur[16];
#pragma unroll
  for (int i = 0; i < 16; ++i) Er[i] = Es[n * SA + q * 16 + i];
#pragma unroll
  for (int i = 0; i < 16; ++i) {
    const int j = q * 16 + i;
    float u = 0.f;
#pragma unroll
    for (int k = 0; k <= KE; ++k) u = fmaf(CTs[k][63 - j], Gs[k * 64 + n], u);
    Ur[i] = u;                    // = Uf[n][j] = (E^{63-j} dB)[n]
  }
  if (rb < BPB) Ss[rb][n] = 0.f;
  const float* xd = xT + ((size_t)d * Bz + z * BPB) * Lz;
  float* Sd = S + (size_t)d * (32 * 8 * 64) + (size_t)(z * BPB) * 64;
#pragma unroll 1
  for (int c = 0; c < 32; ++c) {
    if (rb < BPB) {
      Xs[rb][n] = xd[(size_t)rb * Lz + c * 64 + n];
      Sd[c * 512 + rb * 64 + n] = Ss[rb][n];   // state entering chunk c
    }
    __syncthreads();                            // B1: Xs/Ss ready
    float acc[BPB];
#pragma unroll
    for (int b = 0; b < BPB; ++b) {
      const float4 s0 = *(const float4*)&Ss[b][q * 16 + 0];
      const float4 s1 = *(const float4*)&Ss[b][q * 16 + 4];
      const float4 s2 = *(const float4*)&Ss[b][q * 16 + 8];
      const float4 s3 = *(const float4*)&Ss[b][q * 16 + 12];
      const float4 x0 = *(const float4*)&Xs[b][q * 16 + 0];
      const float4 x1 = *(const float4*)&Xs[b][q * 16 + 4];
      const float4 x2 = *(const float4*)&Xs[b][q * 16 + 8];
      const float4 x3 = *(const float4*)&Xs[b][q * 16 + 12];
      float a = 0.f;
      a = fmaf(Er[0], s0.x, a);  a = fmaf(Er[1], s0.y, a);
      a = fmaf(Er[2], s0.z, a);  a = fmaf(Er[3], s0.w, a);
      a = fmaf(Er[4], s1.x, a);  a = fmaf(Er[5], s1.y, a);
      a = fmaf(Er[6], s1.z, a);  a = fmaf(Er[7], s1.w, a);
      a = fmaf(Er[8], s2.x, a);  a = fmaf(Er[9], s2.y, a);
      a = fmaf(Er[10], s2.z, a); a = fmaf(Er[11], s2.w, a);
      a = fmaf(Er[12], s3.x, a); a = fmaf(Er[13], s3.y, a);
      a = fmaf(Er[14], s3.z, a); a = fmaf(Er[15], s3.w, a);
      a = fmaf(Ur[0], x0.x, a);  a = fmaf(Ur[1], x0.y, a);
      a = fmaf(Ur[2], x0.z, a);  a = fmaf(Ur[3], x0.w, a);
      a = fmaf(Ur[4], x1.x, a);  a = fmaf(Ur[5], x1.y, a);
      a = fmaf(Ur[6], x1.z, a);  a = fmaf(Ur[7], x1.w, a);
      a = fmaf(Ur[8], x2.x, a);  a = fmaf(Ur[9], x2.y, a);
      a = fmaf(Ur[10], x2.z, a); a = fmaf(Ur[11], x2.w, a);
      a = fmaf(Ur[12], x3.x, a); a = fmaf(Ur[13], x3.y, a);
      a = fmaf(Ur[14], x3.z, a); a = fmaf(Ur[15], x3.w, a);
      acc[b] = a;
    }
#pragma unroll
    for (int b = 0; b < BPB; ++b) pr[q][b][n] = acc[b];
    __syncthreads();                            // B2: pr ready
    if (rb < BPB)
      Ss[rb][n] = pr[0][rb][n] + pr[1][rb][n] + pr[2][rb][n] + pr[3][rb][n];
    __syncthreads();                            // B3: Ss updated
  }
}

// Output GEMM v7 (MFMA bf16): per (d, ch) block computes
//   y(64 t x 64 col) = M(64 x 128) . Z^T,  Z[col][k] = [S ; x] in bf16.
// Skip term folded into the Toeplitz diagonal: kx[0] += skip_D[d].
// Fragment pattern identical to gemm4 (validated R14): A[m][quad*8+j],
// B from [n][k] rows, D col=lq row=quad*4+i. Emits yb[d][b][t] bf16.
__global__ __launch_bounds__(256, 4) void s4_out7(
    const float* __restrict__ xT, const float* __restrict__ S,
    const float* __restrict__ Qk, const float* __restrict__ kloc,
    const float* __restrict__ dts, const float* __restrict__ skip_D,
    unsigned short* __restrict__ yb) {
  __shared__ alignas(16) unsigned short Msb[64 * SKB];  // [r(t)][k] bf16
  __shared__ alignas(16) unsigned short Zsb[64 * SKB];  // [col][k] bf16
  __shared__ float Qs[(KE + 1) * Nz];
  __shared__ float CT[KE + 1][66];
  __shared__ unsigned short kxb[64];
  const int d = blockIdx.x;
  const int ch = blockIdx.y;
  const int tid = threadIdx.x;
  const int wave = tid >> 6, lane = tid & 63;
  const int quad = lane >> 4, lq = lane & 15;
  const float dt = dts[d];
  if (tid < 65) {
    const float rdt = (float)tid * dt;
    float c = 1.f;
    CT[0][tid] = 1.f;
#pragma unroll
    for (int k = 1; k <= KE; ++k) { c *= rdt / (float)k; CT[k][tid] = c; }
  }
  for (int idx = tid; idx < (KE + 1) * 64; idx += 256)
    Qs[idx] = Qk[(size_t)d * ((KE + 1) * 64) + idx];
  if (tid < 64)
    kxb[tid] = f2bf(kloc[d * 64 + tid] + ((tid == 0) ? skip_D[d] : 0.f));

  // stage Z = [S ; x] bf16: u-major chunk mapping (2-way LDS stores)
  const float* xd = xT + (size_t)d * Bz * Lz;
  const float* Sd = S + (size_t)d * (32 * 8 * 64);
#pragma unroll
  for (int p = 0; p < 8; ++p) {
    const int u = tid + 256 * p;
    const int col = u >> 5;          // 0..63
    const int sub = u & 31;          // which ushort4 within the col's 128 k
    const int k0 = sub * 4;
    const int bb = col & 7, ccl = col >> 3;
    const int cc = ch * 8 + ccl;
    const float* src = (k0 < 64)
        ? (Sd + cc * 512 + bb * 64 + k0)
        : (xd + (size_t)bb * Lz + cc * 64 + (k0 - 64));
    const float4 v = *(const float4*)src;
    ushort4 o;
    o.x = f2bf(v.x); o.y = f2bf(v.y); o.z = f2bf(v.z); o.w = f2bf(v.w);
    *(ushort4*)&Zsb[col * SKB + k0] = o;
  }
  __syncthreads();   // CT/Qs/kxb ready

  // build M bf16: W part (Horner over Qs) + Toeplitz part (kxb diag-shift)
#pragma unroll
  for (int i = 0; i < 16; ++i) {
    const int e = tid + 256 * i;
    const int r = e >> 6, m = e & 63;
    float w = 0.f;
#pragma unroll
    for (int k = 0; k <= KE; ++k) w = fmaf(CT[k][r + 1], Qs[k * 64 + m], w);
    Msb[r * SKB + m] = f2bf(w);
  }
#pragma unroll
  for (int i = 0; i < 16; ++i) {
    const int e = tid + 256 * i;
    const int r = e >> 6, j = e & 63;
    Msb[r * SKB + 64 + j] = (j <= r) ? kxb[r - j] : (unsigned short)0;
  }
  __syncthreads();   // Msb + Zsb ready

  f32x4 acc[4];
#pragma unroll
  for (int ni = 0; ni < 4; ++ni)
#pragma unroll
    for (int i = 0; i < 4; ++i) acc[ni][i] = 0.f;
#pragma unroll
  for (int ks = 0; ks < 4; ++ks) {
    const bf16x8 af =
        *(const bf16x8*)&Msb[(wave * 16 + lq) * SKB + ks * 32 + quad * 8];
#pragma unroll
    for (int ni = 0; ni < 4; ++ni) {
      const bf16x8 bfr =
          *(const bf16x8*)&Zsb[(ni * 16 + lq) * SKB + ks * 32 + quad * 8];
      acc[ni] = __builtin_amdgcn_mfma_f32_16x16x32_bf16(af, bfr, acc[ni], 0, 0, 0);
    }
  }
  // direct global writeback: row t = wave*16 + quad*4 + i (consecutive i)
#pragma unroll
  for (int ni = 0; ni < 4; ++ni) {
    const int col = ni * 16 + lq;
    const int bb = col & 7, ccl = col >> 3;
    const int cc = ch * 8 + ccl;
    ushort4 o;
    o.x = f2bf(acc[ni][0]); o.y = f2bf(acc[ni][1]);
    o.z = f2bf(acc[ni][2]); o.w = f2bf(acc[ni][3]);
    *(ushort4*)(yb + ((size_t)d * Bz + bb) * Lz + cc * 64 + wave * 16 + quad * 4) = o;
  }
}

// Final GEMM v4 (MFMA bf16): out[row][c] = sum_d yb[d][row] * Wo[c][d] + bo[c]
__global__ __launch_bounds__(256, 2) void s4_gemm4(
    const unsigned short* __restrict__ yb, const float* __restrict__ Wo,
    const float* __restrict__ bo, float* __restrict__ out) {
  __shared__ alignas(16) unsigned short LA[128 * SAK];  // [row(t)][k'(d)]
  __shared__ alignas(16) unsigned short LB[64 * SAK];   // [c][k'(d)]
  const int tid = threadIdx.x;
  const int wave = tid >> 6, lane = tid & 63;
  const int quad = lane >> 4, lq = lane & 15;
  const int r0 = blockIdx.x * 128;
  const int c0 = blockIdx.y * 64;
  const int brow = r0 >> 11, t0 = r0 & 2047;
  const int ad = tid & 31;          // A staging: d-offset 0..31
  const int atp = tid >> 5;         // A staging: t-pair 0..7
  const int bc = tid >> 2;          // B staging: c-offset 0..63
  const int bko = tid & 3;          // B staging: k-octet 0..3
  f32x4 acc[2][4];
#pragma unroll
  for (int mi = 0; mi < 2; ++mi)
#pragma unroll
    for (int ni = 0; ni < 4; ++ni)
#pragma unroll
      for (int i = 0; i < 4; ++i) acc[mi][ni][i] = 0.f;
#pragma unroll 1
  for (int ks = 0; ks < 8; ++ks) {
    const int k0 = ks * 32;
    {
      const unsigned short* src =
          yb + ((size_t)(k0 + ad) * Bz + brow) * Lz + t0 + atp * 16;
#pragma unroll
      for (int h = 0; h < 2; ++h) {
        const bf16x8 v = *(const bf16x8*)(src + h * 8);
#pragma unroll
        for (int j = 0; j < 8; ++j)
          LA[(atp * 16 + h * 8 + j) * SAK + ad] = (unsigned short)v[j];
      }
    }
    {
      const float* wsrc = Wo + (size_t)(c0 + bc) * Dz + k0 + bko * 8;
      const float4 w0 = *(const float4*)(wsrc);
      const float4 w1 = *(const float4*)(wsrc + 4);
      bf16x8 wv;
      wv[0] = (short)f2bf(w0.x); wv[1] = (short)f2bf(w0.y);
      wv[2] = (short)f2bf(w0.z); wv[3] = (short)f2bf(w0.w);
      wv[4] = (short)f2bf(w1.x); wv[5] = (short)f2bf(w1.y);
      wv[6] = (short)f2bf(w1.z); wv[7] = (short)f2bf(w1.w);
      *(bf16x8*)&LB[bc * SAK + bko * 8] = wv;
    }
    __syncthreads();
    bf16x8 af[2], bfr[4];
#pragma unroll
    for (int mi = 0; mi < 2; ++mi)
      af[mi] = *(const bf16x8*)&LA[(wave * 32 + mi * 16 + lq) * SAK + quad * 8];
#pragma unroll
    for (int ni = 0; ni < 4; ++ni)
      bfr[ni] = *(const bf16x8*)&LB[(ni * 16 + lq) * SAK + quad * 8];
#pragma unroll
    for (int mi = 0; mi < 2; ++mi)
#pragma unroll
      for (int ni = 0; ni < 4; ++ni)
        acc[mi][ni] = __builtin_amdgcn_mfma_f32_16x16x32_bf16(
            af[mi], bfr[ni], acc[mi][ni], 0, 0, 0);
    __syncthreads();
  }
  float bb[4];
#pragma unroll
  for (int ni = 0; ni < 4; ++ni) bb[ni] = bo[c0 + ni * 16 + lq];
#pragma unroll
  for (int mi = 0; mi < 2; ++mi)
#pragma unroll
    for (int i = 0; i < 4; ++i) {
      const int row = r0 + wave * 32 + mi * 16 + quad * 4 + i;
#pragma unroll
      for (int ni = 0; ni < 4; ++ni)
        out[(size_t)row * Dz + c0 + ni * 16 + lq] = acc[mi][ni][i] + bb[ni];
    }
}

extern "C" void kernel_launch(void* const* d_in, const int* in_sizes, int n_in,
                              void* d_out, int out_size, void* d_ws, size_t ws_size,
                              hipStream_t stream) {
  const float* x         = (const float*)d_in[0];
  const float* log_A     = (const float*)d_in[1];
  const float* Bp        = (const float*)d_in[2];
  const float* Cp        = (const float*)d_in[3];
  const float* log_delta = (const float*)d_in[4];
  const float* skip_D    = (const float*)d_in[5];
  const float* W_out     = (const float*)d_in[6];
  const float* b_out     = (const float*)d_in[7];
  float* out = (float*)d_out;

  float* xT   = (float*)d_ws;
  float* ybf  = xT + (size_t)Dz * Bz * Lz;       // bf16 yb lives in this slot
  float* S    = ybf + (size_t)Dz * Bz * Lz;
  float* Apow = S + (size_t)Dz * (32 * 8 * 64);
  float* Gk   = Apow + (size_t)8 * 4096;
  float* Qk   = Gk + (size_t)Dz * (KE + 1) * 64;
  float* kloc = Qk + (size_t)Dz * (KE + 1) * 64;
  float* dts  = kloc + (size_t)Dz * 64;
  unsigned short* yb = (unsigned short*)ybf;

  hipLaunchKernelGGL(s4_xt, dim3(Lz / 64, Dz / 64, Bz), dim3(256), 0, stream,
                     x, xT, log_A, Apow);
  hipLaunchKernelGGL(s4_buildpow, dim3(Dz + 3), dim3(256), 0, stream,
                     Apow, Bp, Cp, log_delta, Gk, Qk, kloc, dts);
  hipLaunchKernelGGL(s4_scan4, dim3(Dz, BSP), dim3(256), 0, stream,
                     xT, Apow, Gk, dts, S);
  hipLaunchKernelGGL(s4_out7, dim3(Dz, 4), dim3(256), 0, stream,
                     xT, S, Qk, kloc, dts, skip_D, yb);
  hipLaunchKernelGGL(s4_gemm4, dim3((Bz * Lz) / 128, Dz / 64), dim3(256), 0, stream,
                     yb, W_out, b_out, out);
}

// Round 16
// 150.802 us; speedup vs baseline: 1.7713x; 1.0218x over previous
//
#include <hip/hip_runtime.h>

#define Bz 8
#define Lz 2048
#define Dz 256
#define Nz 64
#define SP 68   // b128-aligned LDS stride (power matmuls)
#define SA 65   // scalar-access LDS stride (conflict-free rows+cols)
#define SAK 72  // gemm5 bf16 LDS stride (ushorts): 64 k + 8 pad
#define SKB 136 // out7 bf16 LDS stride (ushorts)
#define KE 4    // Taylor order: ||64*dt*A|| <= ~0.15 -> rel err ~6e-7
#define KP 7    // p-chain depth = KE + 3 (dB phi1 terms)
#define BSP 4   // scan: blocks per channel (batch split)
#define BPB (Bz / BSP)   // 2 batches per block

typedef __attribute__((ext_vector_type(8))) short bf16x8;
typedef __attribute__((ext_vector_type(4))) float f32x4;

__device__ __forceinline__ float softplusf(float x) {
  return (x > 20.f) ? x : log1pf(expf(x));
}

__device__ __forceinline__ unsigned short f2bf(float f) {  // RNE fp32->bf16
  unsigned int u = __float_as_uint(f);
  u += 0x7fffu + ((u >> 16) & 1u);
  return (unsigned short)(u >> 16);
}

// acc = row n of (LA * LB), cols q*16..q*16+15 (SP strides). No barriers.
__device__ __forceinline__ void pmm_acc(const float* __restrict__ LA,
                                        const float* __restrict__ LB,
                                        float* acc, int n, int q) {
  float arow[64];
#pragma unroll
  for (int mm = 0; mm < 16; ++mm) {
    const float4 a4 = *(const float4*)(LA + n * SP + mm * 4);
    arow[4 * mm + 0] = a4.x; arow[4 * mm + 1] = a4.y;
    arow[4 * mm + 2] = a4.z; arow[4 * mm + 3] = a4.w;
  }
#pragma unroll
  for (int i = 0; i < 16; ++i) acc[i] = 0.f;
#pragma unroll 8
  for (int m = 0; m < 64; ++m) {
    const float4 b0 = *(const float4*)(LB + m * SP + q * 16 + 0);
    const float4 b1 = *(const float4*)(LB + m * SP + q * 16 + 4);
    const float4 b2 = *(const float4*)(LB + m * SP + q * 16 + 8);
    const float4 b3 = *(const float4*)(LB + m * SP + q * 16 + 12);
    const float a = arow[m];
    acc[0]  = fmaf(a, b0.x, acc[0]);  acc[1]  = fmaf(a, b0.y, acc[1]);
    acc[2]  = fmaf(a, b0.z, acc[2]);  acc[3]  = fmaf(a, b0.w, acc[3]);
    acc[4]  = fmaf(a, b1.x, acc[4]);  acc[5]  = fmaf(a, b1.y, acc[5]);
    acc[6]  = fmaf(a, b1.z, acc[6]);  acc[7]  = fmaf(a, b1.w, acc[7]);
    acc[8]  = fmaf(a, b2.x, acc[8]);  acc[9]  = fmaf(a, b2.y, acc[9]);
    acc[10] = fmaf(a, b2.z, acc[10]); acc[11] = fmaf(a, b2.w, acc[11]);
    acc[12] = fmaf(a, b3.x, acc[12]); acc[13] = fmaf(a, b3.y, acc[13]);
    acc[14] = fmaf(a, b3.z, acc[14]); acc[15] = fmaf(a, b3.w, acc[15]);
  }
}

// ---- Transpose x[b][t][d] -> xT[d][b][t] (float4 both sides);
//      folds powinit (Apow[0] = softplus(log_A)). ----
__global__ __launch_bounds__(256) void s4_xt(const float* __restrict__ x,
                                             float* __restrict__ xT,
                                             const float* __restrict__ log_A,
                                             float* __restrict__ Apow) {
  if (blockIdx.x == 0 && blockIdx.y == 0) {
    const int i = blockIdx.z * 512 + threadIdx.x;
    Apow[i] = softplusf(log_A[i]);
    Apow[i + 256] = softplusf(log_A[i + 256]);
  }
  __shared__ float tile[64][69];
  const int t0 = blockIdx.x * 64, d0 = blockIdx.y * 64, b = blockIdx.z;
  const int rr = threadIdx.x >> 4;
  const int c4 = (threadIdx.x & 15) * 4;
#pragma unroll
  for (int p = 0; p < 4; ++p) {
    const int row = p * 16 + rr;
    const float4 v = *(const float4*)(x + ((size_t)b * Lz + t0 + row) * Dz + d0 + c4);
    tile[row][c4 + 0] = v.x; tile[row][c4 + 1] = v.y;
    tile[row][c4 + 2] = v.z; tile[row][c4 + 3] = v.w;
  }
  __syncthreads();
#pragma unroll
  for (int p = 0; p < 4; ++p) {
    const int dd = p * 16 + rr;
    float4 o;
    o.x = tile[c4 + 0][dd]; o.y = tile[c4 + 1][dd];
    o.z = tile[c4 + 2][dd]; o.w = tile[c4 + 3][dd];
    *(float4*)(xT + ((size_t)(d0 + dd) * Bz + b) * Lz + t0 + c4) = o;
  }
}

// ---- fused build + power-basis: blocks 0..255 per-d chains; blocks
//      256..258 compute A2 / A3 / A4 ----
__global__ __launch_bounds__(256, 1) void s4_buildpow(
    float* __restrict__ Apow, const float* __restrict__ Bp,
    const float* __restrict__ Cp, const float* __restrict__ log_delta,
    float* __restrict__ Gk, float* __restrict__ Qk,
    float* __restrict__ kloc, float* __restrict__ dts) {
  __shared__ float As[Nz * SA];
  __shared__ float Pst[KP + 1][Nz];
  __shared__ float Qst[KE + 1][Nz];
  __shared__ float Pv[Nz], Qv[Nz], dBs[Nz];
  __shared__ float prA[4][Nz + 8], prB[4][Nz + 8];
  __shared__ float zp[KE + 1][17], zs[KE + 1];
  __shared__ alignas(16) float PA[Nz * SP];
  __shared__ alignas(16) float PB[Nz * SP];
  const int tid = threadIdx.x;
  const int d = blockIdx.x;
  const int n = tid & 63, qq = tid >> 6;

  if (d >= Dz) {
    const int role = d - Dz;   // 0 -> A2, 1 -> A3 = A*A2, 2 -> A4 = A2*A2
#pragma unroll
    for (int i = 0; i < 4; ++i) {
      const int e = (tid + 256 * i) * 4;
      const int r = e >> 6, c = e & 63;
      const float4 v = *(const float4*)(Apow + e);
      *(float4*)&PA[r * SP + c] = v;
      *(float4*)&PB[r * SP + c] = v;
    }
    __syncthreads();
    float acc[16];
    pmm_acc(PA, PB, acc, n, qq);
    if (role == 0) {
      float* O = Apow + (size_t)1 * 4096;
#pragma unroll
      for (int v = 0; v < 4; ++v) {
        float4 o;
        o.x = acc[4 * v]; o.y = acc[4 * v + 1];
        o.z = acc[4 * v + 2]; o.w = acc[4 * v + 3];
        *(float4*)(O + n * 64 + qq * 16 + 4 * v) = o;
      }
      return;
    }
    __syncthreads();
#pragma unroll
    for (int i = 0; i < 16; ++i) {
      PB[n * SP + qq * 16 + i] = acc[i];
      if (role == 2) PA[n * SP + qq * 16 + i] = acc[i];
    }
    __syncthreads();
    pmm_acc(PA, PB, acc, n, qq);
    float* O = Apow + (size_t)(role + 1) * 4096;
#pragma unroll
    for (int v = 0; v < 4; ++v) {
      float4 o;
      o.x = acc[4 * v]; o.y = acc[4 * v + 1];
      o.z = acc[4 * v + 2]; o.w = acc[4 * v + 3];
      *(float4*)(O + n * 64 + qq * 16 + 4 * v) = o;
    }
    return;
  }

  const float dt = softplusf(log_delta[d]) + 1e-6f;
#pragma unroll
  for (int i = 0; i < 4; ++i) {
    const int e = (tid + 256 * i) * 4;
    const int r = e >> 6, c = e & 63;
    const float4 v = *(const float4*)(Apow + e);
    As[r * SA + c] = v.x; As[r * SA + c + 1] = v.y;
    As[r * SA + c + 2] = v.z; As[r * SA + c + 3] = v.w;
  }
  if (tid < 64) {
    const float bv = Bp[d * Nz + tid], cv = Cp[d * Nz + tid];
    Pv[tid] = bv; Pst[0][tid] = bv;
    Qv[tid] = cv; Qst[0][tid] = cv;
  }
  __syncthreads();
#pragma unroll 1
  for (int k = 1; k <= KP; ++k) {
    float pp = 0.f, pq = 0.f;
#pragma unroll
    for (int mm = 0; mm < 16; ++mm) {
      const int m = qq * 16 + mm;
      pp += As[n * SA + m] * Pv[m];   // (A p)[n]
      pq += As[m * SA + n] * Qv[m];   // (A^T q)[n]
    }
    prA[qq][n] = pp; prB[qq][n] = pq;
    __syncthreads();
    if (tid < 64) {
      const float np = prA[0][tid] + prA[1][tid] + prA[2][tid] + prA[3][tid];
      Pv[tid] = np; Pst[k][tid] = np;
      if (k <= KE) {
        const float nq = prB[0][tid] + prB[1][tid] + prB[2][tid] + prB[3][tid];
        Qv[tid] = nq; Qst[k][tid] = nq;
      }
    }
    __syncthreads();
  }
  const float dtc0 = dt;
  const float dtc1 = dt * dt * 0.5f;
  const float dtc2 = dtc1 * dt * (1.f / 3.f);
  const float dtc3 = dtc2 * dt * 0.25f;
  if (tid < 64) {
    dBs[tid] = dtc0 * Pst[0][tid] + dtc1 * Pst[1][tid] +
               dtc2 * Pst[2][tid] + dtc3 * Pst[3][tid];
#pragma unroll
    for (int k = 0; k <= KE; ++k) {
      Gk[(size_t)d * ((KE + 1) * 64) + k * 64 + tid] =
          dtc0 * Pst[k][tid] + dtc1 * Pst[k + 1][tid] +
          dtc2 * Pst[k + 2][tid] + dtc3 * Pst[k + 3][tid];
      Qk[(size_t)d * ((KE + 1) * 64) + k * 64 + tid] = Qst[k][tid];
    }
  }
  __syncthreads();
  if (tid < (KE + 1) * 16) {
    const int k = tid >> 4, seg = tid & 15;
    float s = 0.f;
#pragma unroll
    for (int i = 0; i < 4; ++i) s += Qst[k][seg * 4 + i] * dBs[seg * 4 + i];
    zp[k][seg] = s;
  }
  __syncthreads();
  if (tid <= KE) {
    float s = 0.f;
#pragma unroll
    for (int seg = 0; seg < 16; ++seg) s += zp[tid][seg];
    zs[tid] = s;
  }
  __syncthreads();
  if (tid < 64) {
    const float rdt = (float)tid * dt;
    float c = 1.f, acc = zs[0];
#pragma unroll
    for (int k = 1; k <= KE; ++k) { c *= rdt / (float)k; acc += c * zs[k]; }
    kloc[d * 64 + tid] = acc;
  }
  if (tid == 0) dts[d] = dt;
}

// Chunked state scan v5: double-buffered Ss/Xs -> 2 barriers per chunk.
// Chain per chunk c (cur=c&1, nxt=cur^1): stage(cur) [same-thread reads
// only] -> B1 -> compute -> pr -> B2 -> reduce into Ss[nxt] (consumed
// same-thread by next stage; broadcast covered by next B1).
__global__ __launch_bounds__(256) void s4_scan5(
    const float* __restrict__ xT, const float* __restrict__ Apow,
    const float* __restrict__ Gk, const float* __restrict__ dts,
    float* __restrict__ S) {
  __shared__ float Es[Nz * SA];
  __shared__ float Gs[(KE + 1) * Nz];
  __shared__ float CTs[KE + 1][66];
  __shared__ alignas(16) float Xs[2][BPB][64];
  __shared__ alignas(16) float Ss[2][BPB][64];
  __shared__ float pr[4][BPB][64];
  const int d = blockIdx.x;
  const int z = blockIdx.y;
  const int tid = threadIdx.x, n = tid & 63, q = tid >> 6;
  const int rb = tid >> 6;               // staging/reduce ownership (rb < BPB)
  const float dt = dts[d];
  if (tid < 65) {
    const float rdt = (float)tid * dt;
    float c = 1.f;
    CTs[0][tid] = 1.f;
#pragma unroll
    for (int k = 1; k <= KE; ++k) { c *= rdt / (float)k; CTs[k][tid] = c; }
  }
  for (int idx = tid; idx < (KE + 1) * 64; idx += 256)
    Gs[idx] = Gk[(size_t)d * ((KE + 1) * 64) + idx];
  {
    float ea[16];
#pragma unroll
    for (int i = 0; i < 16; ++i) ea[i] = 0.f;
    const float dt64 = 64.f * dt;
    float ce = 1.f;
#pragma unroll 1
    for (int k = 1; k <= KE; ++k) {
      ce *= dt64 / (float)k;
      const float* Ak = Apow + (size_t)(k - 1) * 4096;
#pragma unroll
      for (int i = 0; i < 16; ++i)
        ea[i] = fmaf(ce, Ak[tid + 256 * i], ea[i]);
    }
#pragma unroll
    for (int i = 0; i < 16; ++i) {
      const int e = tid + 256 * i;
      const int r = e >> 6, c = e & 63;
      Es[r * SA + c] = ea[i] + ((r == c) ? 1.f : 0.f);
    }
  }
  __syncthreads();
  float Er[16], Ur[16];
#pragma unroll
  for (int i = 0; i < 16; ++i) Er[i] = Es[n * SA + q * 16 + i];
#pragma unroll
  for (int i = 0; i < 16; ++i) {
    const int j = q * 16 + i;
    float u = 0.f;
#pragma unroll
    for (int k = 0; k <= KE; ++k) u = fmaf(CTs[k][63 - j], Gs[k * 64 + n], u);
    Ur[i] = u;                    // = Uf[n][j] = (E^{63-j} dB)[n]
  }
  if (rb < BPB) Ss[0][rb][n] = 0.f;
  const float* xd = xT + ((size_t)d * Bz + z * BPB) * Lz;
  float* Sd = S + (size_t)d * (32 * 8 * 64) + (size_t)(z * BPB) * 64;
#pragma unroll 1
  for (int c = 0; c < 32; ++c) {
    const int cur = c & 1, nxt = cur ^ 1;
    if (rb < BPB) {
      Xs[cur][rb][n] = xd[(size_t)rb * Lz + c * 64 + n];
      Sd[c * 512 + rb * 64 + n] = Ss[cur][rb][n];   // same-thread value
    }
    __syncthreads();                            // B1: Xs/Ss[cur] visible
    float acc[BPB];
#pragma unroll
    for (int b = 0; b < BPB; ++b) {
      const float4 s0 = *(const float4*)&Ss[cur][b][q * 16 + 0];
      const float4 s1 = *(const float4*)&Ss[cur][b][q * 16 + 4];
      const float4 s2 = *(const float4*)&Ss[cur][b][q * 16 + 8];
      const float4 s3 = *(const float4*)&Ss[cur][b][q * 16 + 12];
      const float4 x0 = *(const float4*)&Xs[cur][b][q * 16 + 0];
      const float4 x1 = *(const float4*)&Xs[cur][b][q * 16 + 4];
      const float4 x2 = *(const float4*)&Xs[cur][b][q * 16 + 8];
      const float4 x3 = *(const float4*)&Xs[cur][b][q * 16 + 12];
      float a = 0.f;
      a = fmaf(Er[0], s0.x, a);  a = fmaf(Er[1], s0.y, a);
      a = fmaf(Er[2], s0.z, a);  a = fmaf(Er[3], s0.w, a);
      a = fmaf(Er[4], s1.x, a);  a = fmaf(Er[5], s1.y, a);
      a = fmaf(Er[6], s1.z, a);  a = fmaf(Er[7], s1.w, a);
      a = fmaf(Er[8], s2.x, a);  a = fmaf(Er[9], s2.y, a);
      a = fmaf(Er[10], s2.z, a); a = fmaf(Er[11], s2.w, a);
      a = fmaf(Er[12], s3.x, a); a = fmaf(Er[13], s3.y, a);
      a = fmaf(Er[14], s3.z, a); a = fmaf(Er[15], s3.w, a);
      a = fmaf(Ur[0], x0.x, a);  a = fmaf(Ur[1], x0.y, a);
      a = fmaf(Ur[2], x0.z, a);  a = fmaf(Ur[3], x0.w, a);
      a = fmaf(Ur[4], x1.x, a);  a = fmaf(Ur[5], x1.y, a);
      a = fmaf(Ur[6], x1.z, a);  a = fmaf(Ur[7], x1.w, a);
      a = fmaf(Ur[8], x2.x, a);  a = fmaf(Ur[9], x2.y, a);
      a = fmaf(Ur[10], x2.z, a); a = fmaf(Ur[11], x2.w, a);
      a = fmaf(Ur[12], x3.x, a); a = fmaf(Ur[13], x3.y, a);
      a = fmaf(Ur[14], x3.z, a); a = fmaf(Ur[15], x3.w, a);
      acc[b] = a;
    }
#pragma unroll
    for (int b = 0; b < BPB; ++b) pr[q][b][n] = acc[b];
    __syncthreads();                            // B2: pr visible
    if (rb < BPB)
      Ss[nxt][rb][n] = pr[0][rb][n] + pr[1][rb][n] + pr[2][rb][n] + pr[3][rb][n];
    // no third barrier: next B1 publishes Ss[nxt]; stage read is same-thread
  }
}

// Output GEMM v7 (MFMA bf16): per (d, ch) block computes
//   y(64 t x 64 col) = M(64 x 128) . Z^T,  Z[col][k] = [S ; x] in bf16.
// Skip term folded into the Toeplitz diagonal: kx[0] += skip_D[d].
__global__ __launch_bounds__(256, 4) void s4_out7(
    const float* __restrict__ xT, const float* __restrict__ S,
    const float* __restrict__ Qk, const float* __restrict__ kloc,
    const float* __restrict__ dts, const float* __restrict__ skip_D,
    unsigned short* __restrict__ yb) {
  __shared__ alignas(16) unsigned short Msb[64 * SKB];  // [r(t)][k] bf16
  __shared__ alignas(16) unsigned short Zsb[64 * SKB];  // [col][k] bf16
  __shared__ float Qs[(KE + 1) * Nz];
  __shared__ float CT[KE + 1][66];
  __shared__ unsigned short kxb[64];
  const int d = blockIdx.x;
  const int ch = blockIdx.y;
  const int tid = threadIdx.x;
  const int wave = tid >> 6, lane = tid & 63;
  const int quad = lane >> 4, lq = lane & 15;
  const float dt = dts[d];
  if (tid < 65) {
    const float rdt = (float)tid * dt;
    float c = 1.f;
    CT[0][tid] = 1.f;
#pragma unroll
    for (int k = 1; k <= KE; ++k) { c *= rdt / (float)k; CT[k][tid] = c; }
  }
  for (int idx = tid; idx < (KE + 1) * 64; idx += 256)
    Qs[idx] = Qk[(size_t)d * ((KE + 1) * 64) + idx];
  if (tid < 64)
    kxb[tid] = f2bf(kloc[d * 64 + tid] + ((tid == 0) ? skip_D[d] : 0.f));

  const float* xd = xT + (size_t)d * Bz * Lz;
  const float* Sd = S + (size_t)d * (32 * 8 * 64);
#pragma unroll
  for (int p = 0; p < 8; ++p) {
    const int u = tid + 256 * p;
    const int col = u >> 5;          // 0..63
    const int sub = u & 31;          // which ushort4 within the col's 128 k
    const int k0 = sub * 4;
    const int bb = col & 7, ccl = col >> 3;
    const int cc = ch * 8 + ccl;
    const float* src = (k0 < 64)
        ? (Sd + cc * 512 + bb * 64 + k0)
        : (xd + (size_t)bb * Lz + cc * 64 + (k0 - 64));
    const float4 v = *(const float4*)src;
    ushort4 o;
    o.x = f2bf(v.x); o.y = f2bf(v.y); o.z = f2bf(v.z); o.w = f2bf(v.w);
    *(ushort4*)&Zsb[col * SKB + k0] = o;
  }
  __syncthreads();   // CT/Qs/kxb ready

#pragma unroll
  for (int i = 0; i < 16; ++i) {
    const int e = tid + 256 * i;
    const int r = e >> 6, m = e & 63;
    float w = 0.f;
#pragma unroll
    for (int k = 0; k <= KE; ++k) w = fmaf(CT[k][r + 1], Qs[k * 64 + m], w);
    Msb[r * SKB + m] = f2bf(w);
  }
#pragma unroll
  for (int i = 0; i < 16; ++i) {
    const int e = tid + 256 * i;
    const int r = e >> 6, j = e & 63;
    Msb[r * SKB + 64 + j] = (j <= r) ? kxb[r - j] : (unsigned short)0;
  }
  __syncthreads();   // Msb + Zsb ready

  f32x4 acc[4];
#pragma unroll
  for (int ni = 0; ni < 4; ++ni)
#pragma unroll
    for (int i = 0; i < 4; ++i) acc[ni][i] = 0.f;
#pragma unroll
  for (int ks = 0; ks < 4; ++ks) {
    const bf16x8 af =
        *(const bf16x8*)&Msb[(wave * 16 + lq) * SKB + ks * 32 + quad * 8];
#pragma unroll
    for (int ni = 0; ni < 4; ++ni) {
      const bf16x8 bfr =
          *(const bf16x8*)&Zsb[(ni * 16 + lq) * SKB + ks * 32 + quad * 8];
      acc[ni] = __builtin_amdgcn_mfma_f32_16x16x32_bf16(af, bfr, acc[ni], 0, 0, 0);
    }
  }
#pragma unroll
  for (int ni = 0; ni < 4; ++ni) {
    const int col = ni * 16 + lq;
    const int bb = col & 7, ccl = col >> 3;
    const int cc = ch * 8 + ccl;
    ushort4 o;
    o.x = f2bf(acc[ni][0]); o.y = f2bf(acc[ni][1]);
    o.z = f2bf(acc[ni][2]); o.w = f2bf(acc[ni][3]);
    *(ushort4*)(yb + ((size_t)d * Bz + bb) * Lz + cc * 64 + wave * 16 + quad * 4) = o;
  }
}

// Final GEMM v5 (MFMA bf16, BK=64): halved barrier count vs v4.
// out[row][c] = sum_d yb[d][row] * Wo[c][d] + bo[c]
__global__ __launch_bounds__(256, 2) void s4_gemm5(
    const unsigned short* __restrict__ yb, const float* __restrict__ Wo,
    const float* __restrict__ bo, float* __restrict__ out) {
  __shared__ alignas(16) unsigned short LA[128 * SAK];  // [row(t)][k'(d) 0..63]
  __shared__ alignas(16) unsigned short LB[64 * SAK];   // [c][k'(d) 0..63]
  const int tid = threadIdx.x;
  const int wave = tid >> 6, lane = tid & 63;
  const int quad = lane >> 4, lq = lane & 15;
  const int r0 = blockIdx.x * 128;
  const int c0 = blockIdx.y * 64;
  const int brow = r0 >> 11, t0 = r0 & 2047;
  const int ad = tid & 63;          // A staging: d-offset 0..63
  const int atg = tid >> 6;         // A staging: t-group of 32 (0..3)
  const int bc = tid >> 2;          // B staging: c-offset 0..63
  const int bko = tid & 3;          // B staging: k-octet 0..3 (x2 halves)
  f32x4 acc[2][4];
#pragma unroll
  for (int mi = 0; mi < 2; ++mi)
#pragma unroll
    for (int ni = 0; ni < 4; ++ni)
#pragma unroll
      for (int i = 0; i < 4; ++i) acc[mi][ni][i] = 0.f;
#pragma unroll 1
  for (int ks = 0; ks < 4; ++ks) {
    const int k0 = ks * 64;
    {
      const unsigned short* src =
          yb + ((size_t)(k0 + ad) * Bz + brow) * Lz + t0 + atg * 32;
#pragma unroll
      for (int h = 0; h < 4; ++h) {
        const bf16x8 v = *(const bf16x8*)(src + h * 8);
#pragma unroll
        for (int j = 0; j < 8; ++j)
          LA[(atg * 32 + h * 8 + j) * SAK + ad] = (unsigned short)v[j];
      }
    }
#pragma unroll
    for (int half = 0; half < 2; ++half) {
      const int kk = half * 32 + bko * 8;
      const float* wsrc = Wo + (size_t)(c0 + bc) * Dz + k0 + kk;
      const float4 w0 = *(const float4*)(wsrc);
      const float4 w1 = *(const float4*)(wsrc + 4);
      bf16x8 wv;
      wv[0] = (short)f2bf(w0.x); wv[1] = (short)f2bf(w0.y);
      wv[2] = (short)f2bf(w0.z); wv[3] = (short)f2bf(w0.w);
      wv[4] = (short)f2bf(w1.x); wv[5] = (short)f2bf(w1.y);
      wv[6] = (short)f2bf(w1.z); wv[7] = (short)f2bf(w1.w);
      *(bf16x8*)&LB[bc * SAK + kk] = wv;
    }
    __syncthreads();
#pragma unroll
    for (int ksub = 0; ksub < 2; ++ksub) {
      bf16x8 af[2], bfr[4];
#pragma unroll
      for (int mi = 0; mi < 2; ++mi)
        af[mi] = *(const bf16x8*)
            &LA[(wave * 32 + mi * 16 + lq) * SAK + ksub * 32 + quad * 8];
#pragma unroll
      for (int ni = 0; ni < 4; ++ni)
        bfr[ni] = *(const bf16x8*)
            &LB[(ni * 16 + lq) * SAK + ksub * 32 + quad * 8];
#pragma unroll
      for (int mi = 0; mi < 2; ++mi)
#pragma unroll
        for (int ni = 0; ni < 4; ++ni)
          acc[mi][ni] = __builtin_amdgcn_mfma_f32_16x16x32_bf16(
              af[mi], bfr[ni], acc[mi][ni], 0, 0, 0);
    }
    __syncthreads();
  }
  float bb[4];
#pragma unroll
  for (int ni = 0; ni < 4; ++ni) bb[ni] = bo[c0 + ni * 16 + lq];
#pragma unroll
  for (int mi = 0; mi < 2; ++mi)
#pragma unroll
    for (int i = 0; i < 4; ++i) {
      const int row = r0 + wave * 32 + mi * 16 + quad * 4 + i;
#pragma unroll
      for (int ni = 0; ni < 4; ++ni)
        out[(size_t)row * Dz + c0 + ni * 16 + lq] = acc[mi][ni][i] + bb[ni];
    }
}

extern "C" void kernel_launch(void* const* d_in, const int* in_sizes, int n_in,
                              void* d_out, int out_size, void* d_ws, size_t ws_size,
                              hipStream_t stream) {
  const float* x         = (const float*)d_in[0];
  const float* log_A     = (const float*)d_in[1];
  const float* Bp        = (const float*)d_in[2];
  const float* Cp        = (const float*)d_in[3];
  const float* log_delta = (const float*)d_in[4];
  const float* skip_D    = (const float*)d_in[5];
  const float* W_out     = (const float*)d_in[6];
  const float* b_out     = (const float*)d_in[7];
  float* out = (float*)d_out;

  float* xT   = (float*)d_ws;
  float* ybf  = xT + (size_t)Dz * Bz * Lz;       // bf16 yb lives in this slot
  float* S    = ybf + (size_t)Dz * Bz * Lz;
  float* Apow = S + (size_t)Dz * (32 * 8 * 64);
  float* Gk   = Apow + (size_t)8 * 4096;
  float* Qk   = Gk + (size_t)Dz * (KE + 1) * 64;
  float* kloc = Qk + (size_t)Dz * (KE + 1) * 64;
  float* dts  = kloc + (size_t)Dz * 64;
  unsigned short* yb = (unsigned short*)ybf;

  hipLaunchKernelGGL(s4_xt, dim3(Lz / 64, Dz / 64, Bz), dim3(256), 0, stream,
                     x, xT, log_A, Apow);
  hipLaunchKernelGGL(s4_buildpow, dim3(Dz + 3), dim3(256), 0, stream,
                     Apow, Bp, Cp, log_delta, Gk, Qk, kloc, dts);
  hipLaunchKernelGGL(s4_scan5, dim3(Dz, BSP), dim3(256), 0, stream,
                     xT, Apow, Gk, dts, S);
  hipLaunchKernelGGL(s4_out7, dim3(Dz, 4), dim3(256), 0, stream,
                     xT, S, Qk, kloc, dts, skip_D, yb);
  hipLaunchKernelGGL(s4_gemm5, dim3((Bz * Lz) / 128, Dz / 64), dim3(256), 0, stream,
                     yb, W_out, b_out, out);
}